// Round 3
// baseline (22677.118 us; speedup 1.0000x reference)
//
#include <hip/hip_runtime.h>
#include <math.h>

#define D 256
#define NH 4
#define HDIM 64
#define FFD 2048
#define NL 3
#define VOC 30000
#define BPTT 20
#define BATCH 64
#define SMAX 20
#define BSTR (SMAX*D)        /* 5120 floats per-b activation buffer */
#define NCOLT 118            /* ceil(VOC/256) */
#define NWG 256
#define NTHR 512
#define PS 21                /* score-row stride */
#define HS 65                /* head array stride (bank-conflict pad) */

struct Params {
  const float* image_feats; const int* target; const float* emb_table;
  const float* W_g2e; const float* b_g2e;
  const float* W_out; const float* b_out;
  const float* Wqkv; const float* bqkv;
  const float* Wo;   const float* bo;
  const float* W1;   const float* b1;
  const float* W2;   const float* b2;
  const float* g1;   const float* be1;
  const float* g2;   const float* be2;
  float* out_probs; float* out_words; float* out_eos;
  float* embA; float* xA; float* xB; float* pp; float* fp; float* logits;
  float* pm; float* pd; float* pv; int* pi;
  unsigned* grpcnt; unsigned* globcnt;
};

// ---- device-coherent (LLC) access: bypasses non-coherent per-XCD L2 ----
__device__ __forceinline__ float cld(const float* p) {
  return __hip_atomic_load(p, __ATOMIC_RELAXED, __HIP_MEMORY_SCOPE_AGENT);
}
__device__ __forceinline__ void cst(float* p, float v) {
  __hip_atomic_store(p, v, __ATOMIC_RELAXED, __HIP_MEMORY_SCOPE_AGENT);
}
__device__ __forceinline__ int cldi(const int* p) {
  return __hip_atomic_load(p, __ATOMIC_RELAXED, __HIP_MEMORY_SCOPE_AGENT);
}
__device__ __forceinline__ void csti(int* p, int v) {
  __hip_atomic_store(p, v, __ATOMIC_RELAXED, __HIP_MEMORY_SCOPE_AGENT);
}

__device__ __forceinline__ float wredsum(float s) {
  for (int off = 32; off; off >>= 1) s += __shfl_down(s, off);
  return __shfl(s, 0);
}
__device__ __forceinline__ float wredmax(float m) {
  for (int off = 32; off; off >>= 1) m = fmaxf(m, __shfl_down(m, off));
  return __shfl(m, 0);
}

// group barrier: 4 blocks, monotonic counter, no cache flush (all cross-block
// data moves via cld/cst which are LLC-coherent once vmcnt drains)
__device__ __forceinline__ void grp_wait(unsigned* c, unsigned tgt) {
  asm volatile("s_waitcnt vmcnt(0) lgkmcnt(0)" ::: "memory");
  __syncthreads();
  if (threadIdx.x == 0) {
    __hip_atomic_fetch_add(c, 1u, __ATOMIC_RELAXED, __HIP_MEMORY_SCOPE_AGENT);
    while (__hip_atomic_load(c, __ATOMIC_RELAXED, __HIP_MEMORY_SCOPE_AGENT) < tgt)
      __builtin_amdgcn_s_sleep(1);
  }
  __syncthreads();
  asm volatile("" ::: "memory");
}
// global barrier stage 2: 64 group leaders on one counter, everyone polls
__device__ __forceinline__ void glob_wait(unsigned* g, unsigned tgt, int leader) {
  if (threadIdx.x == 0) {
    if (leader)
      __hip_atomic_fetch_add(g, 1u, __ATOMIC_RELAXED, __HIP_MEMORY_SCOPE_AGENT);
    while (__hip_atomic_load(g, __ATOMIC_RELAXED, __HIP_MEMORY_SCOPE_AGENT) < tgt)
      __builtin_amdgcn_s_sleep(2);
  }
  __syncthreads();
  asm volatile("" ::: "memory");
}

__global__ __launch_bounds__(NTHR) void mega(Params p) {
  // persistent layer-0 q/k/v cache for this block's head (lives whole kernel)
  __shared__ float q0[SMAX*HS], k0[SMAX*HS], v0[SMAX*HS];
  __shared__ float scr[11264];   // 44KB phase-multiplexed scratch
  __shared__ float bc[4];
  __shared__ int   bci[4];

  const int tid = threadIdx.x, wgid = blockIdx.x;
  const int lane = tid & 63, wave = tid >> 6;
  const int b = wgid >> 2, grpj = wgid & 3;
  const int h = grpj;
  unsigned gb = 0, gl = 0;
  unsigned* grpc = p.grpcnt + b*64;
  unsigned* glob = p.globcnt;

  float* embB = p.embA + (long)b*BSTR;
  float* xAb  = p.xA   + (long)b*BSTR;
  float* xBb  = p.xB   + (long)b*BSTR;
  float* ppB  = p.pp   + (long)b*4*BSTR;
  float* fpB  = p.fp   + (long)b*4*BSTR;
  float* lgB  = p.logits + (long)b*VOC;

  // scratch aliases (attention phase)
  float* xs  = scr;            // 5120: staged input rows
  float* qsL = scr + 5120;     // 1300
  float* ksL = scr + 6420;     // 1300
  float* vsL = scr + 7720;     // 1300
  float* ps  = scr + 9020;     // 420
  float* os  = scr + 9440;     // 1300 (+overrun pad: rows<24 stay in scr)

  float vx1[4], vx2[4];        // register-carried residual rows (wave*4+grpj)

  // ================= init: img_embed row 0, cols grpj*64.. =================
  {
    for (int idx = tid; idx < 2048; idx += NTHR)
      scr[idx] = p.image_feats[b*2048 + idx];
    __syncthreads();
    int c = tid & 63, kg = tid >> 6;
    int col = grpj*64 + c;
    float s = 0.f;
#pragma unroll 4
    for (int k = kg*256; k < kg*256 + 256; ++k)
      s += scr[k] * p.W_g2e[(long)k*D + col];
    scr[2048 + kg*64 + c] = s;
    __syncthreads();
    if (tid < 64) {
      float a = 0.f;
      for (int kg2 = 0; kg2 < 8; ++kg2) a += scr[2048 + kg2*64 + tid];
      cst(&embB[grpj*64 + tid], a + p.b_g2e[grpj*64 + tid]);
    }
  }
  ++gb; grp_wait(grpc, gb*4u);

  // ================= decode =================
  for (int i = 0; i < BPTT; ++i) {
    const int S = i + 1;
    for (int l = 0; l < NL; ++l) {
      float *qq, *kq, *vq;
      if (l == 0) {
        // new-row qkv for head h into persistent cache
        if (tid < D) xs[tid] = cld(&embB[(long)i*D + tid]);
        __syncthreads();
        if (tid < 192) {
          int strip = tid / 64, d = tid % 64;
          int col = strip*D + h*HDIM + d;
          float a = 0.f;
#pragma unroll 4
          for (int k = 0; k < D; ++k) a += xs[k] * p.Wqkv[(long)k*768 + col];
          a += p.bqkv[col];
          float* dst = strip == 0 ? q0 : strip == 1 ? k0 : v0;
          dst[i*HS + d] = a;
        }
        __syncthreads();
        qq = q0; kq = k0; vq = v0;
      } else {
        const float* W  = p.Wqkv + (long)l*D*768;
        const float* bl = p.bqkv + l*768;
        for (int idx = tid; idx < S*D; idx += NTHR) xs[idx] = cld(&xBb[idx]);
        __syncthreads();
        if (tid < 480) {
          int colq = tid % 48, rowg = tid / 48;
          int strip = colq / 16, dbase = (colq % 16)*4;
          int col = strip*D + h*HDIM + dbase;
          int r0 = rowg*2;
          if (r0 < S) {
            float acc[2][4] = {};
#pragma unroll 4
            for (int k = 0; k < D; ++k) {
              float4 w = *(const float4*)&W[(long)k*768 + col];
              float a0 = xs[r0*D + k], a1 = xs[(r0+1)*D + k];
              acc[0][0]+=a0*w.x; acc[0][1]+=a0*w.y; acc[0][2]+=a0*w.z; acc[0][3]+=a0*w.w;
              acc[1][0]+=a1*w.x; acc[1][1]+=a1*w.y; acc[1][2]+=a1*w.z; acc[1][3]+=a1*w.w;
            }
            float* dst = strip == 0 ? qsL : strip == 1 ? ksL : vsL;
#pragma unroll
            for (int rr = 0; rr < 2; ++rr) if (r0 + rr < S)
#pragma unroll
              for (int c = 0; c < 4; ++c)
                dst[(r0+rr)*HS + dbase + c] = acc[rr][c] + bl[col + c];
          }
        }
        __syncthreads();
        qq = qsL; kq = ksL; vq = vsL;
      }
      // scores
      for (int idx = tid; idx < S*S; idx += NTHR) {
        int si = idx / S, ti = idx - si*S;
        float a = 0.f;
#pragma unroll 8
        for (int k = 0; k < HDIM; ++k) a += qq[si*HS+k] * kq[ti*HS+k];
        ps[si*PS + ti] = a * 0.125f;
      }
      __syncthreads();
      // softmax (wave per row)
      for (int r = wave; r < S; r += 8) {
        float v = (lane < S) ? ps[r*PS + lane] : -1e30f;
        float m = wredmax(v);
        float e = (lane < S) ? expf(v - m) : 0.f;
        float ss = wredsum(e);
        if (lane < S) ps[r*PS + lane] = e / ss;
      }
      __syncthreads();
      // PV
      for (int idx = tid; idx < S*HDIM; idx += NTHR) {
        int s2 = idx >> 6, d = idx & 63;
        float a = 0.f;
        for (int t2 = 0; t2 < S; ++t2) a += ps[s2*PS + t2] * vq[t2*HS + d];
        os[s2*HS + d] = a;
      }
      __syncthreads();
      // proj partial (K = this head's 64 rows of Wo)
      {
        const float* Wol = p.Wo + (long)l*D*D + (long)h*HDIM*D;
        int c0 = lane*4;
        float acc[3][4] = {};
#pragma unroll 4
        for (int k = 0; k < HDIM; ++k) {
          float4 w = *(const float4*)&Wol[(long)k*D + c0];
#pragma unroll
          for (int jj = 0; jj < 3; ++jj) {
            float a = os[(wave + 8*jj)*HS + k];
            acc[jj][0]+=a*w.x; acc[jj][1]+=a*w.y; acc[jj][2]+=a*w.z; acc[jj][3]+=a*w.w;
          }
        }
#pragma unroll
        for (int jj = 0; jj < 3; ++jj) {
          int r = wave + 8*jj;
          if (r < S)
#pragma unroll
            for (int c = 0; c < 4; ++c)
              cst(&ppB[(grpj*SMAX + r)*D + c0 + c], acc[jj][c]);
        }
      }
      ++gb; grp_wait(grpc, gb*4u);

      // LN1: row r = wave*4+grpj; residual from regs (l>0) or embeds (l==0)
      {
        int r = wave*4 + grpj, c0 = lane*4;
        if (r < S) {
          const float* bol = p.bo + l*D;
          const float* g1l = p.g1 + l*D; const float* be1l = p.be1 + l*D;
          float v4[4];
#pragma unroll
          for (int c = 0; c < 4; ++c) {
            float resid = (l == 0) ? cld(&embB[(long)r*D + c0 + c]) : vx2[c];
            float s = resid + bol[c0 + c];
#pragma unroll
            for (int j2 = 0; j2 < 4; ++j2)
              s += cld(&ppB[(j2*SMAX + r)*D + c0 + c]);
            v4[c] = s;
          }
          float s = v4[0]+v4[1]+v4[2]+v4[3];
          float mu = wredsum(s) * (1.f/D);
          float q2 = 0.f;
#pragma unroll
          for (int c = 0; c < 4; ++c) { float dv = v4[c]-mu; q2 += dv*dv; }
          float var = wredsum(q2) * (1.f/D);
          float inv = 1.f/sqrtf(var + 1e-5f);
#pragma unroll
          for (int c = 0; c < 4; ++c) {
            float y = (v4[c]-mu)*inv*g1l[c0+c] + be1l[c0+c];
            vx1[c] = y;
            cst(&xAb[(long)r*D + c0 + c], y);
          }
        }
      }
      ++gb; grp_wait(grpc, gb*4u);

      // FF: block handles ff chunks 2*grpj, 2*grpj+1; K-partials in regs
      {
        float* xAs = scr; float* ffs = scr + 5120;
        for (int idx = tid; idx < S*D; idx += NTHR) xAs[idx] = cld(&xAb[idx]);
        __syncthreads();
        const float* W1l = p.W1 + (long)l*D*FFD;
        const float* b1l = p.b1 + (long)l*FFD;
        const float* W2l = p.W2 + (long)l*FFD*D;
        int c0 = lane*4;
        float accO[3][4] = {};
        for (int y = 2*grpj; y < 2*grpj + 2; ++y) {
          int f0 = y*256;
          float acc1[3][4] = {};
#pragma unroll 4
          for (int k = 0; k < D; ++k) {
            float4 w = *(const float4*)&W1l[(long)k*FFD + f0 + c0];
#pragma unroll
            for (int jj = 0; jj < 3; ++jj) {
              float a = xAs[(wave + 8*jj)*D + k];
              acc1[jj][0]+=a*w.x; acc1[jj][1]+=a*w.y; acc1[jj][2]+=a*w.z; acc1[jj][3]+=a*w.w;
            }
          }
#pragma unroll
          for (int jj = 0; jj < 3; ++jj) {
            int r = wave + 8*jj;
#pragma unroll
            for (int c = 0; c < 4; ++c)
              ffs[r*D + c0 + c] = fmaxf(acc1[jj][c] + b1l[f0 + c0 + c], 0.f);
          }
          __syncthreads();
#pragma unroll 4
          for (int k = 0; k < D; ++k) {
            float4 w = *(const float4*)&W2l[(long)(f0 + k)*D + c0];
#pragma unroll
            for (int jj = 0; jj < 3; ++jj) {
              float a = ffs[(wave + 8*jj)*D + k];
              accO[jj][0]+=a*w.x; accO[jj][1]+=a*w.y; accO[jj][2]+=a*w.z; accO[jj][3]+=a*w.w;
            }
          }
          __syncthreads();
        }
#pragma unroll
        for (int jj = 0; jj < 3; ++jj) {
          int r = wave + 8*jj;
          if (r < S)
#pragma unroll
            for (int c = 0; c < 4; ++c)
              cst(&fpB[(grpj*SMAX + r)*D + c0 + c], accO[jj][c]);
        }
      }
      ++gb; grp_wait(grpc, gb*4u);

      // LN2
      {
        int r = wave*4 + grpj, c0 = lane*4;
        if (r < S) {
          const float* b2l = p.b2 + l*D;
          const float* g2l = p.g2 + l*D; const float* be2l = p.be2 + l*D;
          float v4[4];
#pragma unroll
          for (int c = 0; c < 4; ++c) {
            float s = vx1[c] + b2l[c0 + c];
#pragma unroll
            for (int j2 = 0; j2 < 4; ++j2)
              s += cld(&fpB[(j2*SMAX + r)*D + c0 + c]);
            v4[c] = s;
          }
          float s = v4[0]+v4[1]+v4[2]+v4[3];
          float mu = wredsum(s) * (1.f/D);
          float q2 = 0.f;
#pragma unroll
          for (int c = 0; c < 4; ++c) { float dv = v4[c]-mu; q2 += dv*dv; }
          float var = wredsum(q2) * (1.f/D);
          float inv = 1.f/sqrtf(var + 1e-5f);
#pragma unroll
          for (int c = 0; c < 4; ++c) {
            float y = (v4[c]-mu)*inv*g2l[c0+c] + be2l[c0+c];
            vx2[c] = y;
            cst(&xBb[(long)r*D + c0 + c], y);
          }
        }
      }
      if (l + 1 < NL) { ++gb; grp_wait(grpc, gb*4u); }
    } // layers

    // GB1: encoder outputs visible everywhere
    ++gb; grp_wait(grpc, gb*4u);
    ++gl; glob_wait(glob, gl*64u, grpj == 0);

    // F: logits = xB[last row of each b] @ W_out  (global: 236 tiles)
    if (wgid < 2*NCOLT) {
      float* As = scr;  // 32 x 256
      int rowt = wgid & 1, colt = wgid >> 1;
      for (int idx = tid; idx < 32*D; idx += NTHR) {
        int rr = idx >> 8, c = idx & 255;
        As[idx] = cld(&p.xB[(long)(rowt*32 + rr)*BSTR + (long)i*D + c]);
      }
      __syncthreads();
      int col = colt*256 + lane*4;
      int colL = col > VOC-4 ? VOC-4 : col;
      bool valid = col < VOC;
      float acc[4][4] = {};
#pragma unroll 4
      for (int k = 0; k < D; ++k) {
        float4 w = *(const float4*)&p.W_out[(long)k*VOC + colL];
#pragma unroll
        for (int jj = 0; jj < 4; ++jj) {
          float a = As[(wave*4 + jj)*D + k];
          acc[jj][0]+=a*w.x; acc[jj][1]+=a*w.y; acc[jj][2]+=a*w.z; acc[jj][3]+=a*w.w;
        }
      }
      float4 bv = *(const float4*)&p.b_out[colL];
#pragma unroll
      for (int jj = 0; jj < 4; ++jj) {
        int bb = rowt*32 + wave*4 + jj;
        float v4[4]; float lm = -1e30f;
        v4[0]=acc[jj][0]+bv.x; v4[1]=acc[jj][1]+bv.y; v4[2]=acc[jj][2]+bv.z; v4[3]=acc[jj][3]+bv.w;
        if (valid) {
#pragma unroll
          for (int c = 0; c < 4; ++c) {
            cst(&p.logits[(long)bb*VOC + col + c], v4[c]);
            lm = fmaxf(lm, v4[c]);
          }
        }
        float m = wredmax(lm);
        float ls = 0.f;
        if (valid) { for (int c = 0; c < 4; ++c) ls += expf(v4[c] - m); }
        for (int off = 32; off; off >>= 1) ls += __shfl_down(ls, off);
        float av = -1e30f; int ai = VOC;
        if (valid) {
#pragma unroll
          for (int c = 0; c < 4; ++c) if (v4[c] > av) { av = v4[c]; ai = col + c; }
        }
        for (int off = 32; off; off >>= 1) {
          float av2 = __shfl_down(av, off); int ai2 = __shfl_down(ai, off);
          if (av2 > av || (av2 == av && ai2 < ai)) { av = av2; ai = ai2; }
        }
        if (lane == 0) {
          int pidx = colt*64 + bb;
          cst(&p.pm[pidx], m); cst(&p.pd[pidx], ls);
          cst(&p.pv[pidx], av); csti(&p.pi[pidx], ai);
        }
      }
    }
    // GB2: logits + partials visible
    ++gb; grp_wait(grpc, gb*4u);
    ++gl; glob_wait(glob, gl*64u, grpj == 0);

    // G: per-b merge (redundant on 4 blocks), probs, outputs, next embed
    {
      float* Lm = scr; float* Ld = scr + 128; float* Lv = scr + 256;
      int* Li = (int*)(scr + 384);
      if (tid < NCOLT) {
        Lm[tid] = cld(&p.pm[tid*64 + b]);
        Ld[tid] = cld(&p.pd[tid*64 + b]);
        Lv[tid] = cld(&p.pv[tid*64 + b]);
        Li[tid] = cldi(&p.pi[tid*64 + b]);
      }
      __syncthreads();
      if (tid == 0) {
        float gmax = -1e30f;
        for (int t2 = 0; t2 < NCOLT; ++t2) gmax = fmaxf(gmax, Lm[t2]);
        float Ssum = 0.f;
        for (int t2 = 0; t2 < NCOLT; ++t2) Ssum += Ld[t2] * expf(Lm[t2] - gmax);
        float bvv = -1e30f; int bi = VOC;
        for (int t2 = 0; t2 < NCOLT; ++t2)
          if (Lv[t2] > bvv || (Lv[t2] == bvv && Li[t2] < bi)) { bvv = Lv[t2]; bi = Li[t2]; }
        int run = 1;
        for (int jj = 1; jj <= i; ++jj) if (p.target[b*BPTT + jj] == 2) run = 0;
        bc[0] = gmax; bc[1] = Ssum; bci[0] = bi; bci[1] = run;
      }
      __syncthreads();
      float gmax = bc[0], Ssum = bc[1];
      int ei = bci[0], run = bci[1];
      for (int idx = tid; idx < 7500; idx += NTHR) {
        int c = grpj*7500 + idx;
        float lv = cld(&lgB[c]);
        float pr = expf(lv - gmax) / Ssum;
        if (c == 2) p.out_eos[b*BPTT + i] = pr;
        float* op = &p.out_probs[(long)b*VOC + c];   // block-private cols: plain ld/st
        if (i == 0) *op = pr;
        else if (run) *op = fmaxf(*op, pr);
      }
      if (grpj == 0 && tid == 0) p.out_words[b*BPTT + i] = run ? (float)ei : 0.f;
      if (grpj == 0 && i + 1 < BPTT && tid < D)
        cst(&embB[(long)(i+1)*D + tid], p.emb_table[(long)ei*D + tid]);
    }
    ++gb; grp_wait(grpc, gb*4u);
  } // steps
}

// ---------------- host ----------------
extern "C" void kernel_launch(void* const* d_in, const int* in_sizes, int n_in,
                              void* d_out, int out_size, void* d_ws, size_t ws_size,
                              hipStream_t stream) {
  Params P;
  P.image_feats = (const float*)d_in[0];
  P.target      = (const int*)  d_in[1];
  P.emb_table   = (const float*)d_in[2];
  P.W_g2e       = (const float*)d_in[3];
  P.b_g2e       = (const float*)d_in[4];
  P.W_out       = (const float*)d_in[5];
  P.b_out       = (const float*)d_in[6];
  P.Wqkv        = (const float*)d_in[7];
  P.bqkv        = (const float*)d_in[8];
  P.Wo          = (const float*)d_in[9];
  P.bo          = (const float*)d_in[10];
  P.W1          = (const float*)d_in[11];
  P.b1          = (const float*)d_in[12];
  P.W2          = (const float*)d_in[13];
  P.b2          = (const float*)d_in[14];
  P.g1          = (const float*)d_in[15];
  P.be1         = (const float*)d_in[16];
  P.g2          = (const float*)d_in[17];
  P.be2         = (const float*)d_in[18];

  float* out_probs = (float*)d_out;
  P.out_probs = out_probs;
  P.out_words = out_probs + (long)BATCH*VOC;
  P.out_eos   = P.out_words + BATCH*BPTT;

  char* ws = (char*)d_ws;
  P.embA   = (float*)ws;  ws += sizeof(float)*(long)BATCH*BSTR;
  P.xA     = (float*)ws;  ws += sizeof(float)*(long)BATCH*BSTR;
  P.xB     = (float*)ws;  ws += sizeof(float)*(long)BATCH*BSTR;
  P.pp     = (float*)ws;  ws += sizeof(float)*(long)BATCH*4*BSTR;
  P.fp     = (float*)ws;  ws += sizeof(float)*(long)BATCH*4*BSTR;
  P.logits = (float*)ws;  ws += sizeof(float)*(long)BATCH*VOC;
  P.pm     = (float*)ws;  ws += sizeof(float)*NCOLT*64;
  P.pd     = (float*)ws;  ws += sizeof(float)*NCOLT*64;
  P.pv     = (float*)ws;  ws += sizeof(float)*NCOLT*64;
  P.pi     = (int*)ws;    ws += sizeof(int)*NCOLT*64;
  P.grpcnt = (unsigned*)ws; ws += sizeof(unsigned)*64*64;
  P.globcnt= (unsigned*)ws; ws += sizeof(unsigned)*64;

  // counters must be zero every launch (bench replays)
  hipMemsetAsync(P.grpcnt, 0, sizeof(unsigned)*(64*64 + 64), stream);

  void* args[] = { &P };
  hipError_t err = hipLaunchCooperativeKernel((void*)mega, dim3(NWG), dim3(NTHR),
                                              args, 0, stream);
  if (err != hipSuccess) {
    // 256 blocks x 512thr x ~61KB LDS = 1 block/CU on 256 CUs: co-resident
    hipLaunchKernelGGL(mega, dim3(NWG), dim3(NTHR), 0, stream, P);
  }
}

// Round 4
// 12986.172 us; speedup vs baseline: 1.7463x; 1.7463x over previous
//
#include <hip/hip_runtime.h>
#include <math.h>

#define D 256
#define NH 4
#define HDIM 64
#define FFD 2048
#define NL 3
#define VOC 30000
#define BPTT 20
#define BATCH 64
#define NMAX (BPTT*BATCH)   /* 1280 */
#define NCOLT 118           /* ceil(VOC/256) vocab column tiles */
#define TROWS 32            /* GEMM tile rows */
#define NWG 256

struct Params {
  const float* image_feats;
  const int*   target;
  const float* emb_table;
  const float* W_g2e; const float* b_g2e;
  const float* W_out; const float* b_out;
  const float* Wqkv; const float* bqkv;
  const float* Wo;   const float* bo;
  const float* W1;   const float* b1;
  const float* W2;   const float* b2;
  const float* g1;   const float* be1;
  const float* g2;   const float* be2;
  float* out_probs; float* out_words; float* out_eos;
  float* embeds; float* xbuf; float* qkvb0; float* qkvb; float* obuf;
  float* pbuf; float* logits;
  float* pm; float* pd; float* pv; float* gS;
  int* pi; int* maskS;
  unsigned* flags;
};

// ---- device-coherent (cross-XCD) scalar access: bypass non-coherent L2 ----
__device__ __forceinline__ float cld(const float* p) {
  return __hip_atomic_load(p, __ATOMIC_RELAXED, __HIP_MEMORY_SCOPE_AGENT);
}
__device__ __forceinline__ void cst(float* p, float v) {
  __hip_atomic_store(p, v, __ATOMIC_RELAXED, __HIP_MEMORY_SCOPE_AGENT);
}
__device__ __forceinline__ int cldi(const int* p) {
  return __hip_atomic_load(p, __ATOMIC_RELAXED, __HIP_MEMORY_SCOPE_AGENT);
}
__device__ __forceinline__ void csti(int* p, int v) {
  __hip_atomic_store(p, v, __ATOMIC_RELAXED, __HIP_MEMORY_SCOPE_AGENT);
}

// ---- grid barrier: per-block flag on its own cacheline; ZERO atomic RMWs.
// Arrive: block writes its epoch (parallel across blocks). Wait: thread t polls
// flag[t]; __syncthreads_and combines. Data correctness: producers' cst stores
// are LLC-visible after the vmcnt drain that precedes the flag store; consumers
// read via cld after the dependent poll-exit branch.
__device__ __forceinline__ void gbar(unsigned* flags, unsigned epoch) {
  asm volatile("s_waitcnt vmcnt(0) lgkmcnt(0)" ::: "memory");
  __syncthreads();
  if (threadIdx.x == 0)
    __hip_atomic_store(&flags[(unsigned)blockIdx.x * 32u], epoch,
                       __ATOMIC_RELAXED, __HIP_MEMORY_SCOPE_AGENT);
  int ok;
  do {
    int mine = 1;
    if (threadIdx.x < NWG)
      mine = ((int)(__hip_atomic_load(&flags[(unsigned)threadIdx.x * 32u],
                    __ATOMIC_RELAXED, __HIP_MEMORY_SCOPE_AGENT) - epoch) >= 0);
    ok = __syncthreads_and(mine);
    if (!ok) __builtin_amdgcn_s_sleep(1);
  } while (!ok);
  asm volatile("" ::: "memory");
}

// ---- stage 32 rows x 256 features into LDS (coherent source) ----
__device__ __forceinline__ void stage32(float (*As)[D], const float* src, long row0) {
  const int tid = threadIdx.x;
#pragma unroll 4
  for (int j = 0; j < TROWS; ++j)
    As[j][tid] = cld(src + (row0 + j)*(long)D + tid);
}

// ---- 32x256 @ 256xM tile: thread (colg,tokg) -> rows tokg*8+j, cols col..col+3
__device__ __forceinline__ void mm32(const float (*As)[D], const float* __restrict__ Wp,
                                     int M, float acc[8][4]) {
  const int r0 = (threadIdx.x >> 6) * 8;
  for (int kk = 0; kk < D; kk += 4) {
    float w[4][4];
#pragma unroll
    for (int q = 0; q < 4; ++q)
      *(float4*)w[q] = *(const float4*)(Wp + (long)(kk+q)*M);
#pragma unroll
    for (int j = 0; j < 8; ++j) {
      float a[4];
      *(float4*)a = *(const float4*)&As[r0+j][kk];
#pragma unroll
      for (int c = 0; c < 4; ++c)
#pragma unroll
        for (int q = 0; q < 4; ++q)
          acc[j][c] += a[q]*w[q][c];
    }
  }
}

__global__ __launch_bounds__(256) void mega(Params p) {
  extern __shared__ char smraw[];
  float (*As)[D] = (float(*)[D])smraw;                     // 32KB
  float (*Bs)[D] = (float(*)[D])(smraw + TROWS*D*4);       // 32KB
  const int tid = threadIdx.x, wgid = blockIdx.x, nwg = gridDim.x;
  const int colg = tid & 63, tokg = tid >> 6;
  unsigned ep = 0;
  unsigned* flags = p.flags;

  // ================= init: img embed (blocks 0..63) =================
  if (wgid < BATCH) {
    float* xs = (float*)smraw;
    int b = wgid;
    for (int j = 0; j < 8; ++j) xs[tid + j*256] = p.image_feats[b*2048 + tid + j*256];
    __syncthreads();
    float acc = 0.f;
    for (int k = 0; k < 2048; k += 4) {
      float4 xv = *(const float4*)&xs[k];
      acc += xv.x * p.W_g2e[(k+0)*D + tid];
      acc += xv.y * p.W_g2e[(k+1)*D + tid];
      acc += xv.z * p.W_g2e[(k+2)*D + tid];
      acc += xv.w * p.W_g2e[(k+3)*D + tid];
    }
    cst(&p.embeds[(long)b*D + tid], acc + p.b_g2e[tid]);
  }
  gbar(flags, ++ep);

  // ================= decode loop =================
  for (int i = 0; i < BPTT; ++i) {
    const int S = i + 1, N = S * BATCH;

    // ---- PH1: A0 (layer-0 qkv for NEW 64 rows; cached across steps)
    //          blocks 118..123. || H(i-1): out_probs update, blocks 0..117.
    if (wgid >= NCOLT && wgid < NCOLT + 6) {
      int idx = wgid - NCOLT;
      int tt = idx & 1, cp = idx >> 1;
      long row0 = (long)i*BATCH + tt*TROWS;
      stage32(As, p.embeds, row0);
      __syncthreads();
      float acc[8][4] = {};
      int col = cp*256 + colg*4;
      mm32(As, p.Wqkv + col, 3*D, acc);
      float bv[4]; *(float4*)bv = *(const float4*)(p.bqkv + col);
      for (int j = 0; j < 8; ++j) {
        long row = row0 + tokg*8 + j;
        for (int c = 0; c < 4; ++c)
          cst(&p.qkvb0[row*(3*D) + col + c], acc[j][c] + bv[c]);
      }
    } else if (wgid < NCOLT && i > 0) {
      float* gm = (float*)smraw; float* ss = gm + 64; int* mk = (int*)(ss + 64);
      if (tid < 64) {
        gm[tid] = cld(&p.gS[tid*2]); ss[tid] = cld(&p.gS[tid*2+1]);
        mk[tid] = cldi(&p.maskS[tid]);
      }
      __syncthreads();
      int col = wgid*256 + colg*4;
      if (col < VOC) {
        for (int j = 0; j < 16; ++j) {
          int b = tokg*16 + j;
          if (i-1 == 0 || mk[b]) {
            for (int c = 0; c < 4; ++c) {
              float l = cld(&p.logits[(long)b*VOC + col + c]);
              float pr = expf(l - gm[b]) / ss[b];
              float* op = &p.out_probs[(long)b*VOC + col + c];
              if (i-1 == 0) *op = pr; else *op = fmaxf(*op, pr);
            }
          }
        }
      }
    }
    gbar(flags, ++ep);

    for (int l = 0; l < NL; ++l) {
      // ---- B: attention, block = (b,h), 256 blocks exactly ----
      {
        const float* src = (l == 0) ? p.qkvb0 : p.qkvb;
        float* qs = (float*)smraw;
        float* ks = qs + BPTT*HDIM;
        float* vs = ks + BPTT*HDIM;
        float* ps = vs + BPTT*HDIM;
        int b = wgid & 63, h = wgid >> 6;
        int d = tid & 63, g4 = tid >> 6;
        for (int s = g4; s < S; s += 4) {
          long base = (long)(s*BATCH + b)*(3*D) + h*HDIM + d;
          qs[s*HDIM+d] = cld(&src[base]);
          ks[s*HDIM+d] = cld(&src[base + D]);
          vs[s*HDIM+d] = cld(&src[base + 2*D]);
        }
        __syncthreads();
        for (int q = tid; q < S*S; q += 256) {
          int si = q / S, ti = q - si*S;
          float acc = 0.f;
#pragma unroll 4
          for (int k = 0; k < HDIM; ++k) acc += qs[si*HDIM+k]*ks[ti*HDIM+k];
          ps[si*(BPTT+1)+ti] = acc * 0.125f;
        }
        __syncthreads();
        if (tid < S) {
          float m = -1e30f;
          for (int t2 = 0; t2 < S; ++t2) m = fmaxf(m, ps[tid*(BPTT+1)+t2]);
          float sum = 0.f;
          for (int t2 = 0; t2 < S; ++t2) {
            float e = expf(ps[tid*(BPTT+1)+t2] - m);
            ps[tid*(BPTT+1)+t2] = e; sum += e;
          }
          float inv = 1.f/sum;
          for (int t2 = 0; t2 < S; ++t2) ps[tid*(BPTT+1)+t2] *= inv;
        }
        __syncthreads();
        for (int s = g4; s < S; s += 4) {
          float acc = 0.f;
          for (int t2 = 0; t2 < S; ++t2) acc += ps[s*(BPTT+1)+t2]*vs[t2*HDIM+d];
          cst(&p.obuf[(long)(s*BATCH+b)*D + h*HDIM + d], acc);
        }
      }
      gbar(flags, ++ep);

      // ---- C: proj + LN1 ; tiles = 2S (T=32) ----
      {
        const float* Xres = (l == 0) ? p.embeds : p.xbuf;
        const float* Wl = p.Wo + (long)l*D*D;
        const float* bol = p.bo + l*D;
        const float* g1l = p.g1 + l*D; const float* be1l = p.be1 + l*D;
        for (int t = wgid; t < 2*S; t += nwg) {
          long row0 = (long)t*TROWS;
          stage32(As, p.obuf, row0);
          __syncthreads();
          float acc[8][4] = {};
          int col = colg*4;
          mm32(As, Wl + col, D, acc);
          for (int j = 0; j < 8; ++j) {
            long tok = row0 + tokg*8 + j;
            float v[4];
            for (int c = 0; c < 4; ++c)
              v[c] = acc[j][c] + cld(&Xres[tok*D + col + c]) + bol[col + c];
            float s = v[0]+v[1]+v[2]+v[3];
            for (int off = 32; off; off >>= 1) s += __shfl_down(s, off);
            float mu = __shfl(s, 0) * (1.f/D);
            float q2 = 0.f;
            for (int c = 0; c < 4; ++c) { float dv = v[c]-mu; q2 += dv*dv; }
            for (int off = 32; off; off >>= 1) q2 += __shfl_down(q2, off);
            float var = __shfl(q2, 0) * (1.f/D);
            float inv = 1.f/sqrtf(var + 1e-5f);
            for (int c = 0; c < 4; ++c)
              cst(&p.xbuf[tok*D + col + c], (v[c]-mu)*inv*g1l[col+c] + be1l[col+c]);
          }
          __syncthreads();
        }
      }
      gbar(flags, ++ep);

      // ---- D: ff1(relu)+ff2-partial; XCD-stable map: y = wgid&7 (== XCD
      //      under %8 placement) so each XCD re-reads only its own 512KB
      //      W1/W2 slice every step; row-tiles cycle over slot = wgid>>3 ----
      {
        const float* W1l = p.W1 + (long)l*D*FFD;
        const float* b1l = p.b1 + (long)l*FFD;
        const float* W2l = p.W2 + (long)l*FFD*D;
        const int y = wgid & 7, slot = wgid >> 3;
        for (int tt = slot; tt < 2*S; tt += 32) {
          long row0 = (long)tt*TROWS;
          stage32(As, p.xbuf, row0);
          __syncthreads();
          float acc[8][4] = {};
          int fcol = y*256 + colg*4;
          mm32(As, W1l + fcol, FFD, acc);
          float bv[4]; *(float4*)bv = *(const float4*)(b1l + fcol);
          for (int j = 0; j < 8; ++j)
            for (int c = 0; c < 4; ++c)
              Bs[tokg*8+j][colg*4+c] = fmaxf(acc[j][c] + bv[c], 0.f);
          __syncthreads();
          float acc2[8][4] = {};
          int col = colg*4;
          mm32(Bs, W2l + (long)(y*256)*D + col, D, acc2);
          for (int j = 0; j < 8; ++j) {
            long tok = row0 + tokg*8 + j;
            for (int c = 0; c < 4; ++c)
              cst(&p.pbuf[((long)y*NMAX + tok)*D + col + c], acc2[j][c]);
          }
          __syncthreads();
        }
      }
      gbar(flags, ++ep);

      // ---- E: x = LN2(x + sum(8 chunks) + b2) ; per-token waves ----
      {
        const float* b2l = p.b2 + l*D;
        const float* g2l = p.g2 + l*D; const float* be2l = p.be2 + l*D;
        for (long tk = wgid*4 + tokg; tk < N; tk += (long)nwg*4) {
          int c0 = colg*4;
          float v[4];
          for (int c = 0; c < 4; ++c) v[c] = cld(&p.xbuf[tk*D + c0 + c]) + b2l[c0+c];
          for (int y = 0; y < 8; ++y)
            for (int c = 0; c < 4; ++c)
              v[c] += cld(&p.pbuf[((long)y*NMAX + tk)*D + c0 + c]);
          float s = v[0]+v[1]+v[2]+v[3];
          for (int off = 32; off; off >>= 1) s += __shfl_down(s, off);
          float mu = __shfl(s, 0) * (1.f/D);
          float q2 = 0.f;
          for (int c = 0; c < 4; ++c) { float dv = v[c]-mu; q2 += dv*dv; }
          for (int off = 32; off; off >>= 1) q2 += __shfl_down(q2, off);
          float var = __shfl(q2, 0) * (1.f/D);
          float inv = 1.f/sqrtf(var + 1e-5f);
          for (int c = 0; c < 4; ++c)
            cst(&p.xbuf[tk*D + c0 + c], (v[c]-mu)*inv*g2l[c0+c] + be2l[c0+c]);
        }
      }
      gbar(flags, ++ep);

      // ---- A(l+1): qkv for next layer ; tiles = 6S ----
      if (l + 1 < NL) {
        const float* Wl = p.Wqkv + (long)(l+1)*D*3*D;
        const float* bl = p.bqkv + (long)(l+1)*3*D;
        for (int t = wgid; t < 6*S; t += nwg) {
          int tt = t % (2*S), cp = t / (2*S);
          long row0 = (long)tt*TROWS;
          stage32(As, p.xbuf, row0);
          __syncthreads();
          float acc[8][4] = {};
          int col = cp*256 + colg*4;
          mm32(As, Wl + col, 3*D, acc);
          float bv[4]; *(float4*)bv = *(const float4*)(bl + col);
          for (int j = 0; j < 8; ++j) {
            long row = row0 + tokg*8 + j;
            for (int c = 0; c < 4; ++c)
              cst(&p.qkvb[row*(3*D) + col + c], acc[j][c] + bv[c]);
          }
          __syncthreads();
        }
        gbar(flags, ++ep);
      }
    } // layers

    // ---- F: logits (2 row-tiles x 118 col-tiles) + slice partials.
    //      XCD-stable swizzle: colt = (slot>>1)*8 + (wgid&7) keeps both
    //      row-tiles of a W_out column slice on one XCD (L2-resident). ----
    {
      long arow0 = (long)i*BATCH;
      const int x = wgid & 7, slot = wgid >> 3;
      const int rowt = slot & 1, cq = slot >> 1;
      const int colt = cq*8 + x;
      if (cq < 15 && colt < NCOLT) {
        stage32(As, p.xbuf, arow0 + rowt*TROWS);
        __syncthreads();
        int col = colt*256 + colg*4;
        int colL = col > VOC-4 ? VOC-4 : col;
        float acc[8][4] = {};
        mm32(As, p.W_out + colL, VOC, acc);
        float bv[4]; *(float4*)bv = *(const float4*)(p.b_out + colL);
        bool valid = (col < VOC);
        for (int j = 0; j < 8; ++j) {
          int b = rowt*TROWS + tokg*8 + j;
          float v[4];
          float lm = -1e30f;
          for (int c = 0; c < 4; ++c) {
            v[c] = acc[j][c] + bv[c];
            if (valid) { cst(&p.logits[(long)b*VOC + col + c], v[c]); lm = fmaxf(lm, v[c]); }
          }
          float m = lm;
          for (int off = 32; off; off >>= 1) m = fmaxf(m, __shfl_down(m, off));
          m = __shfl(m, 0);
          float ls = 0.f;
          if (valid) for (int c = 0; c < 4; ++c) ls += expf(v[c] - m);
          for (int off = 32; off; off >>= 1) ls += __shfl_down(ls, off);
          float av = -1e30f; int ai = VOC;
          if (valid) for (int c = 0; c < 4; ++c) if (v[c] > av) { av = v[c]; ai = col + c; }
          for (int off = 32; off; off >>= 1) {
            float av2 = __shfl_down(av, off); int ai2 = __shfl_down(ai, off);
            if (av2 > av || (av2 == av && ai2 < ai)) { av = av2; ai = ai2; }
          }
          if (colg == 0) {
            int pidx = colt*64 + b;
            cst(&p.pm[pidx], m);
            cst(&p.pd[pidx], ls);
            cst(&p.pv[pidx], av);
            csti(&p.pi[pidx], ai);
          }
        }
      }
    }
    gbar(flags, ++ep);

    // ---- G: per-b merge of 118 slice partials; outputs + next embed ----
    if (wgid < BATCH) {
      int b = wgid;
      float* Lm = (float*)smraw;
      float* Ld = Lm + 128;
      float* Lv = Ld + 128;
      int*   Li = (int*)(Lv + 128);
      int*   Lei = Li + 128;
      if (tid < NCOLT) {
        Lm[tid] = cld(&p.pm[tid*64 + b]);
        Ld[tid] = cld(&p.pd[tid*64 + b]);
        Lv[tid] = cld(&p.pv[tid*64 + b]);
        Li[tid] = cldi(&p.pi[tid*64 + b]);
      }
      __syncthreads();
      if (tid == 0) {
        float gmax = -1e30f;
        for (int t2 = 0; t2 < NCOLT; ++t2) gmax = fmaxf(gmax, Lm[t2]);
        float Ssum = 0.f;
        for (int t2 = 0; t2 < NCOLT; ++t2) Ssum += Ld[t2] * expf(Lm[t2] - gmax);
        float bvv = -1e30f; int bi = VOC;
        for (int t2 = 0; t2 < NCOLT; ++t2)
          if (Lv[t2] > bvv || (Lv[t2] == bvv && Li[t2] < bi)) { bvv = Lv[t2]; bi = Li[t2]; }
        int run = 1;
        for (int j = 1; j <= i; ++j) if (p.target[b*BPTT + j] == 2) run = 0;
        float p2 = expf(cld(&p.logits[(long)b*VOC + 2]) - gmax) / Ssum;
        p.out_eos[b*BPTT + i] = p2;
        p.out_words[b*BPTT + i] = run ? (float)bi : 0.f;
        cst(&p.gS[b*2], gmax);
        cst(&p.gS[b*2+1], Ssum);
        csti(&p.maskS[b], run);
        Lei[0] = bi;
      }
      __syncthreads();
      if (i + 1 < BPTT) {
        int ei = Lei[0];
        cst(&p.embeds[((long)(i+1)*BATCH + b)*D + tid], p.emb_table[(long)ei*D + tid]);
      }
    }
    gbar(flags, ++ep);
  } // steps

  // ---- final H: out_probs update for step 19 ----
  if (wgid < NCOLT) {
    float* gm = (float*)smraw; float* ss = gm + 64; int* mk = (int*)(ss + 64);
    if (tid < 64) {
      gm[tid] = cld(&p.gS[tid*2]); ss[tid] = cld(&p.gS[tid*2+1]);
      mk[tid] = cldi(&p.maskS[tid]);
    }
    __syncthreads();
    int col = wgid*256 + colg*4;
    if (col < VOC) {
      for (int j = 0; j < 16; ++j) {
        int b = tokg*16 + j;
        if (mk[b]) {
          for (int c = 0; c < 4; ++c) {
            float l = cld(&p.logits[(long)b*VOC + col + c]);
            float pr = expf(l - gm[b]) / ss[b];
            float* op = &p.out_probs[(long)b*VOC + col + c];
            *op = fmaxf(*op, pr);
          }
        }
      }
    }
  }
}

// ---------------- host ----------------
extern "C" void kernel_launch(void* const* d_in, const int* in_sizes, int n_in,
                              void* d_out, int out_size, void* d_ws, size_t ws_size,
                              hipStream_t stream) {
  Params P;
  P.image_feats = (const float*)d_in[0];
  P.target      = (const int*)  d_in[1];
  P.emb_table   = (const float*)d_in[2];
  P.W_g2e       = (const float*)d_in[3];
  P.b_g2e       = (const float*)d_in[4];
  P.W_out       = (const float*)d_in[5];
  P.b_out       = (const float*)d_in[6];
  P.Wqkv        = (const float*)d_in[7];
  P.bqkv        = (const float*)d_in[8];
  P.Wo          = (const float*)d_in[9];
  P.bo          = (const float*)d_in[10];
  P.W1          = (const float*)d_in[11];
  P.b1          = (const float*)d_in[12];
  P.W2          = (const float*)d_in[13];
  P.b2          = (const float*)d_in[14];
  P.g1          = (const float*)d_in[15];
  P.be1        = (const float*)d_in[16];
  P.g2          = (const float*)d_in[17];
  P.be2         = (const float*)d_in[18];

  float* out_probs = (float*)d_out;
  P.out_probs = out_probs;
  P.out_words = out_probs + (long)BATCH*VOC;
  P.out_eos   = P.out_words + BATCH*BPTT;

  char* ws = (char*)d_ws;
  P.embeds = (float*)ws;  ws += sizeof(float)*(long)NMAX*D;
  P.xbuf   = (float*)ws;  ws += sizeof(float)*(long)NMAX*D;
  P.qkvb0  = (float*)ws;  ws += sizeof(float)*(long)NMAX*3*D;
  P.qkvb   = (float*)ws;  ws += sizeof(float)*(long)NMAX*3*D;
  P.obuf   = (float*)ws;  ws += sizeof(float)*(long)NMAX*D;
  P.pbuf   = (float*)ws;  ws += sizeof(float)*(long)8*NMAX*D;
  P.logits = (float*)ws;  ws += sizeof(float)*(long)BATCH*VOC;
  P.pm     = (float*)ws;  ws += sizeof(float)*NCOLT*64;
  P.pd     = (float*)ws;  ws += sizeof(float)*NCOLT*64;
  P.pv     = (float*)ws;  ws += sizeof(float)*NCOLT*64;
  P.gS     = (float*)ws;  ws += sizeof(float)*128;
  P.pi     = (int*)ws;    ws += sizeof(int)*NCOLT*64;
  P.maskS  = (int*)ws;    ws += sizeof(int)*64;
  P.flags  = (unsigned*)ws; ws += sizeof(unsigned)*NWG*32;

  static bool inited = false;
  if (!inited) {
    hipFuncSetAttribute((const void*)mega,
                        hipFuncAttributeMaxDynamicSharedMemorySize, 65536);
    inited = true;
  }

  hipMemsetAsync(P.flags, 0, sizeof(unsigned)*NWG*32, stream);
  void* args[] = { &P };
  hipError_t err = hipLaunchCooperativeKernel((void*)mega, dim3(NWG), dim3(256),
                                              args, 65536, stream);
  if (err != hipSuccess) {
    // 256 blocks x 64KB LDS = 1 block/CU on 256 CUs: co-resident by capacity.
    hipLaunchKernelGGL(mega, dim3(NWG), dim3(256), 65536, stream, P);
  }
}

// Round 5
// 10529.607 us; speedup vs baseline: 2.1537x; 1.2333x over previous
//
#include <hip/hip_runtime.h>
#include <math.h>

#define D 256
#define NH 4
#define HDIM 64
#define FFD 2048
#define NL 3
#define VOC 30000
#define BPTT 20
#define BATCH 64
#define NMAX (BPTT*BATCH)   /* 1280 */
#define NCOLT 118           /* ceil(VOC/256) */
#define TROWS 32
#define NWG 256
#define NTHR 512

struct Params {
  const float* image_feats; const int* target; const float* emb_table;
  const float* W_g2e; const float* b_g2e;
  const float* W_out; const float* b_out;
  const float* Wqkv; const float* bqkv;
  const float* Wo;   const float* bo;
  const float* W1;   const float* b1;
  const float* W2;   const float* b2;
  const float* g1;   const float* be1;
  const float* g2;   const float* be2;
  float* out_probs; float* out_words; float* out_eos;
  float* embeds; float* xcur; float* xln1; float* qkvb0; float* qkvb;
  float* pp; float* fp; float* logits;
  float* pm; float* pd; float* pv; float* gS;
  int* pi; int* maskS;
  unsigned* flags;
};

// ---- device-coherent (cross-XCD) access via LLC ----
__device__ __forceinline__ float cld(const float* p) {
  return __hip_atomic_load(p, __ATOMIC_RELAXED, __HIP_MEMORY_SCOPE_AGENT);
}
__device__ __forceinline__ void cst(float* p, float v) {
  __hip_atomic_store(p, v, __ATOMIC_RELAXED, __HIP_MEMORY_SCOPE_AGENT);
}
__device__ __forceinline__ int cldi(const int* p) {
  return __hip_atomic_load(p, __ATOMIC_RELAXED, __HIP_MEMORY_SCOPE_AGENT);
}
__device__ __forceinline__ void csti(int* p, int v) {
  __hip_atomic_store(p, v, __ATOMIC_RELAXED, __HIP_MEMORY_SCOPE_AGENT);
}

__device__ __forceinline__ float wredsum(float s) {
  for (int off = 32; off; off >>= 1) s += __shfl_down(s, off);
  return __shfl(s, 0);
}
__device__ __forceinline__ float wredmax(float m) {
  for (int off = 32; off; off >>= 1) m = fmaxf(m, __shfl_down(m, off));
  return __shfl(m, 0);
}

// ---- flag-array grid barrier (r4-verified): zero RMWs, no cache flush ----
__device__ __forceinline__ void gbar(unsigned* flags, unsigned epoch) {
  asm volatile("s_waitcnt vmcnt(0) lgkmcnt(0)" ::: "memory");
  __syncthreads();
  if (threadIdx.x == 0)
    __hip_atomic_store(&flags[(unsigned)blockIdx.x * 32u], epoch,
                       __ATOMIC_RELAXED, __HIP_MEMORY_SCOPE_AGENT);
  int ok;
  do {
    int mine = 1;
    if (threadIdx.x < NWG)
      mine = ((int)(__hip_atomic_load(&flags[(unsigned)threadIdx.x * 32u],
                    __ATOMIC_RELAXED, __HIP_MEMORY_SCOPE_AGENT) - epoch) >= 0);
    ok = __syncthreads_and(mine);
    if (!ok) __builtin_amdgcn_s_sleep(1);
  } while (!ok);
  asm volatile("" ::: "memory");
}

// ---- stage 32x256 rows plain (coherent src) ----
__device__ __forceinline__ void stage32(float (*As)[D], const float* src, long row0) {
  for (int idx = threadIdx.x; idx < TROWS*D; idx += NTHR) {
    int r = idx >> 8, c = idx & 255;
    As[r][c] = cld(src + (row0 + r)*(long)D + c);
  }
}

// ---- stage 32 rows with fused residual+partials sum and LayerNorm ----
// As[r][c] = LN(resid[row]+bias + sum_q parts[q][row]) * g + be ; optionally
// writes the LN output to wr (coherent) for downstream residual use.
__device__ __forceinline__ void stageLN(float (*As)[D], const float* resid, long row0,
    const float* parts, int nparts, long pstride,
    const float* bias, const float* g, const float* be, float* wr) {
  const int tid = threadIdx.x;
  for (int idx = tid; idx < TROWS*D; idx += NTHR) {
    int r = idx >> 8, c = idx & 255;
    long row = row0 + r;
    float v = cld(resid + row*D + c) + bias[c];
    for (int q = 0; q < nparts; ++q)
      v += cld(parts + (long)q*pstride + row*D + c);
    As[r][c] = v;
  }
  __syncthreads();
  const int lane = tid & 63, w = tid >> 6;
#pragma unroll
  for (int j = 0; j < 4; ++j) {
    int r = w*4 + j;
    float4 x = *(float4*)&As[r][lane*4];
    float mu = wredsum(x.x+x.y+x.z+x.w) * (1.f/D);
    float dx = x.x-mu, dy = x.y-mu, dz = x.z-mu, dw = x.w-mu;
    float var = wredsum(dx*dx+dy*dy+dz*dz+dw*dw) * (1.f/D);
    float inv = 1.f/sqrtf(var + 1e-5f);
    float4 gg = *(const float4*)&g[lane*4];
    float4 bb = *(const float4*)&be[lane*4];
    float4 o;
    o.x = dx*inv*gg.x + bb.x; o.y = dy*inv*gg.y + bb.y;
    o.z = dz*inv*gg.z + bb.z; o.w = dw*inv*gg.w + bb.w;
    *(float4*)&As[r][lane*4] = o;
    if (wr) {
      long row = row0 + r;
      cst(&wr[row*D + lane*4 + 0], o.x);
      cst(&wr[row*D + lane*4 + 1], o.y);
      cst(&wr[row*D + lane*4 + 2], o.z);
      cst(&wr[row*D + lane*4 + 3], o.w);
    }
  }
  __syncthreads();
}

// ---- 32x256 @ 256xM tile with 512 threads: wave w rows w*4+j, lane cols lane*4..+3
__device__ __forceinline__ void mm32w(const float (*As)[D], const float* __restrict__ Wp,
                                      long M, float acc[4][4]) {
  const int r0 = (threadIdx.x >> 6) * 4;
  for (int kk = 0; kk < D; kk += 4) {
    float w[4][4];
#pragma unroll
    for (int q = 0; q < 4; ++q)
      *(float4*)w[q] = *(const float4*)(Wp + (long)(kk+q)*M);
#pragma unroll
    for (int j = 0; j < 4; ++j) {
      float a[4];
      *(float4*)a = *(const float4*)&As[r0+j][kk];
#pragma unroll
      for (int c = 0; c < 4; ++c)
#pragma unroll
        for (int q = 0; q < 4; ++q)
          acc[j][c] += a[q]*w[q][c];
    }
  }
}

__global__ __launch_bounds__(NTHR, 2) void mega(Params p) {
  extern __shared__ char smraw[];
  float (*As)[D] = (float(*)[D])smraw;                 // 32KB
  float (*Bs)[D] = (float(*)[D])(smraw + TROWS*D*4);   // 32KB
  float* sm = (float*)smraw;
  const int tid = threadIdx.x, wgid = blockIdx.x;
  const int lane = tid & 63, wave = tid >> 6;
  unsigned ep = 0;
  unsigned* flags = p.flags;

  // ================= init: img embed (blocks 0..63), exact r4 math ========
  if (wgid < BATCH) {
    int b = wgid;
    for (int idx = tid; idx < 2048; idx += NTHR) sm[idx] = p.image_feats[b*2048 + idx];
    __syncthreads();
    if (tid < D) {
      float acc = 0.f;
      for (int k = 0; k < 2048; k += 4) {
        float4 xv = *(const float4*)&sm[k];
        acc += xv.x * p.W_g2e[(k+0)*D + tid];
        acc += xv.y * p.W_g2e[(k+1)*D + tid];
        acc += xv.z * p.W_g2e[(k+2)*D + tid];
        acc += xv.w * p.W_g2e[(k+3)*D + tid];
      }
      cst(&p.embeds[(long)b*D + tid], acc + p.b_g2e[tid]);
    }
  }
  gbar(flags, ++ep);

  // ================= decode loop =================
  for (int i = 0; i < BPTT; ++i) {
    const int S = i + 1;

    // ---- PH1: A0 new-row qkv (blocks 118..123) || H(i-1) probs (0..117) ----
    if (wgid >= NCOLT && wgid < NCOLT + 6) {
      int idx = wgid - NCOLT;
      int tt = idx & 1, cp = idx >> 1;
      long row0 = (long)i*BATCH + tt*TROWS;
      stage32(As, p.embeds, row0);
      __syncthreads();
      float acc[4][4] = {};
      int col = cp*256 + lane*4;
      mm32w(As, p.Wqkv + col, 3*D, acc);
      float bv[4]; *(float4*)bv = *(const float4*)(p.bqkv + col);
      const int r0 = wave*4;
      for (int j = 0; j < 4; ++j) {
        long row = row0 + r0 + j;
        for (int c = 0; c < 4; ++c)
          cst(&p.qkvb0[row*768 + col + c], acc[j][c] + bv[c]);
      }
    } else if (wgid < NCOLT && i > 0) {
      float* gm = sm; float* ss = sm + 64; int* mk = (int*)(sm + 128);
      if (tid < 64) {
        gm[tid] = cld(&p.gS[tid*2]); ss[tid] = cld(&p.gS[tid*2+1]);
        mk[tid] = cldi(&p.maskS[tid]);
      }
      __syncthreads();
      int cbase = wgid*256;
      for (int idx = tid; idx < BATCH*256; idx += NTHR) {
        int b = idx >> 8, c = cbase + (idx & 255);
        if (c < VOC && (i-1 == 0 || mk[b])) {
          float l = cld(&p.logits[(long)b*VOC + c]);
          float pr = expf(l - gm[b]) / ss[b];
          float* op = &p.out_probs[(long)b*VOC + c];
          if (i-1 == 0) *op = pr; else *op = fmaxf(*op, pr);
        }
      }
    }
    gbar(flags, ++ep);

    for (int l = 0; l < NL; ++l) {
      // ---- B: attention + per-head proj partial (block = (b,h)) ----
      {
        const float* src = (l == 0) ? p.qkvb0 : p.qkvb;
        float* qs = sm; float* ks = sm + 1280; float* vs = sm + 2560;
        float* ps = sm + 3840;
        int b = wgid & 63, h = wgid >> 6;
        for (int idx = tid; idx < S*HDIM; idx += NTHR) {
          int s = idx >> 6, d = idx & 63;
          long base = (long)(s*BATCH + b)*768 + h*HDIM + d;
          qs[idx] = cld(&src[base]);
          ks[idx] = cld(&src[base + D]);
          vs[idx] = cld(&src[base + 2*D]);
        }
        __syncthreads();
        const float* Wo2 = p.Wo + (long)l*D*D + (long)h*HDIM*D;
        if (l < NL-1) {
          for (int idx = tid; idx < S*S; idx += NTHR) {
            int si = idx / S, ti = idx - si*S;
            float a = 0.f;
#pragma unroll 8
            for (int k = 0; k < HDIM; ++k) a += qs[si*HDIM+k]*ks[ti*HDIM+k];
            ps[si*(BPTT+1)+ti] = a * 0.125f;
          }
          __syncthreads();
          for (int r = wave; r < S; r += 8) {
            float v = (lane < S) ? ps[r*(BPTT+1)+lane] : -1e30f;
            float m = wredmax(v);
            float e = (lane < S) ? expf(v - m) : 0.f;
            float ssum = wredsum(e);
            if (lane < S) ps[r*(BPTT+1)+lane] = e / ssum;
          }
          __syncthreads();
          for (int idx = tid; idx < S*HDIM; idx += NTHR) {
            int s = idx >> 6, d = idx & 63;
            float a = 0.f;
            for (int t2 = 0; t2 < S; ++t2) a += ps[s*(BPTT+1)+t2]*vs[t2*HDIM+d];
            qs[idx] = a;   // o overwrites q (q dead after scores)
          }
          __syncthreads();
          int c0 = lane*4;
          float acc[3][4] = {};
          for (int k = 0; k < HDIM; ++k) {
            float4 w = *(const float4*)&Wo2[(long)k*D + c0];
#pragma unroll
            for (int jj = 0; jj < 3; ++jj) {
              int r = wave + 8*jj;
              float a = (r < S) ? qs[r*HDIM + k] : 0.f;
              acc[jj][0]+=a*w.x; acc[jj][1]+=a*w.y; acc[jj][2]+=a*w.z; acc[jj][3]+=a*w.w;
            }
          }
          for (int jj = 0; jj < 3; ++jj) {
            int r = wave + 8*jj;
            if (r < S) {
              long row = (long)r*BATCH + b;
              for (int c = 0; c < 4; ++c)
                cst(&p.pp[((long)h*NMAX + row)*D + c0 + c], acc[jj][c]);
            }
          }
        } else {
          // l==2: only the last q-row (s=i) is ever consumed
          if (tid < S) {
            float a = 0.f;
            for (int k = 0; k < HDIM; ++k) a += qs[i*HDIM+k]*ks[tid*HDIM+k];
            ps[tid] = a * 0.125f;
          }
          __syncthreads();
          if (wave == 0) {
            float v = (lane < S) ? ps[lane] : -1e30f;
            float m = wredmax(v);
            float e = (lane < S) ? expf(v - m) : 0.f;
            float ssum = wredsum(e);
            if (lane < S) ps[lane] = e / ssum;
          }
          __syncthreads();
          if (tid < HDIM) {
            float a = 0.f;
            for (int t2 = 0; t2 < S; ++t2) a += ps[t2]*vs[t2*HDIM+tid];
            qs[tid] = a;
          }
          __syncthreads();
          if (tid < D) {
            float a = 0.f;
            for (int k = 0; k < HDIM; ++k) a += qs[k]*Wo2[(long)k*D + tid];
            cst(&p.pp[((long)h*NMAX + (long)i*BATCH + b)*D + tid], a);
          }
        }
      }
      gbar(flags, ++ep);

      // ---- D: LN1-fused stage + ff1(relu) + ff2 partial ----
      {
        const float* resid = (l == 0) ? p.embeds : p.xcur;
        const float* bol = p.bo + l*D;
        const float* g1l = p.g1 + l*D; const float* be1l = p.be1 + l*D;
        const float* W1l = p.W1 + (long)l*D*FFD;
        const float* b1l = p.b1 + (long)l*FFD;
        const float* W2l = p.W2 + (long)l*FFD*D;
        const int y = wgid & 7, slot = wgid >> 3;
        const int nrt = (l == NL-1) ? 2 : 2*S;
        const long rbase = (l == NL-1) ? (long)i*BATCH : 0;
        for (int tt = slot; tt < nrt; tt += 32) {
          long row0 = rbase + (long)tt*TROWS;
          stageLN(As, resid, row0, p.pp, 4, (long)NMAX*D, bol, g1l, be1l,
                  (y == 0) ? p.xln1 : nullptr);
          float acc1[4][4] = {};
          int fcol = y*256 + lane*4;
          mm32w(As, W1l + fcol, FFD, acc1);
          float bv[4]; *(float4*)bv = *(const float4*)(b1l + fcol);
          const int r0 = wave*4;
          for (int j = 0; j < 4; ++j)
            for (int c = 0; c < 4; ++c)
              Bs[r0+j][lane*4+c] = fmaxf(acc1[j][c] + bv[c], 0.f);
          __syncthreads();
          float acc2[4][4] = {};
          mm32w(Bs, W2l + (long)(y*256)*D + lane*4, D, acc2);
          for (int j = 0; j < 4; ++j) {
            long row = row0 + r0 + j;
            for (int c = 0; c < 4; ++c)
              cst(&p.fp[((long)y*NMAX + row)*D + lane*4 + c], acc2[j][c]);
          }
          __syncthreads();
        }
      }
      gbar(flags, ++ep);

      // ---- AE (l<2): LN2-fused stage + qkv for layer l+1 ----
      if (l + 1 < NL) {
        const float* b2l = p.b2 + l*D;
        const float* g2l = p.g2 + l*D; const float* be2l = p.be2 + l*D;
        const float* Wl = p.Wqkv + (long)(l+1)*D*768;
        const float* bl = p.bqkv + (long)(l+1)*768;
        for (int t = wgid; t < 6*S; t += NWG) {
          int tt = t % (2*S), cp = t / (2*S);
          long row0 = (long)tt*TROWS;
          stageLN(As, p.xln1, row0, p.fp, 8, (long)NMAX*D, b2l, g2l, be2l,
                  (cp == 0) ? p.xcur : nullptr);
          float acc[4][4] = {};
          int col = cp*256 + lane*4;
          mm32w(As, Wl + col, 768, acc);
          float bv[4]; *(float4*)bv = *(const float4*)(bl + col);
          const int r0 = wave*4;
          for (int j = 0; j < 4; ++j) {
            long row = row0 + r0 + j;
            for (int c = 0; c < 4; ++c)
              cst(&p.qkvb[row*768 + col + c], acc[j][c] + bv[c]);
          }
          __syncthreads();
        }
        gbar(flags, ++ep);
      }
    } // layers

    // ---- F: LN2-fused stage + logits tiles (XCD-stable colt swizzle) ----
    {
      const float* b2l = p.b2 + (NL-1)*D;
      const float* g2l = p.g2 + (NL-1)*D; const float* be2l = p.be2 + (NL-1)*D;
      const int x = wgid & 7, slot = wgid >> 3;
      const int rowt = slot & 1, cq = slot >> 1;
      const int colt = cq*8 + x;
      if (cq < 15 && colt < NCOLT) {
        long row0 = (long)i*BATCH + rowt*TROWS;
        stageLN(As, p.xln1, row0, p.fp, 8, (long)NMAX*D, b2l, g2l, be2l, nullptr);
        int col = colt*256 + lane*4;
        int colL = col > VOC-4 ? VOC-4 : col;
        float acc[4][4] = {};
        mm32w(As, p.W_out + colL, VOC, acc);
        float bv[4]; *(float4*)bv = *(const float4*)(p.b_out + colL);
        bool valid = (col < VOC);
        const int r0 = wave*4;
        for (int j = 0; j < 4; ++j) {
          int b = rowt*TROWS + r0 + j;
          float v4[4]; float lm = -1e30f;
          for (int c = 0; c < 4; ++c) {
            v4[c] = acc[j][c] + bv[c];
            if (valid) { cst(&p.logits[(long)b*VOC + col + c], v4[c]); lm = fmaxf(lm, v4[c]); }
          }
          float m = wredmax(lm);
          float ls = 0.f;
          if (valid) for (int c = 0; c < 4; ++c) ls += expf(v4[c] - m);
          for (int off = 32; off; off >>= 1) ls += __shfl_down(ls, off);
          float av = -1e30f; int ai = VOC;
          if (valid) for (int c = 0; c < 4; ++c) if (v4[c] > av) { av = v4[c]; ai = col + c; }
          for (int off = 32; off; off >>= 1) {
            float av2 = __shfl_down(av, off); int ai2 = __shfl_down(ai, off);
            if (av2 > av || (av2 == av && ai2 < ai)) { av = av2; ai = ai2; }
          }
          if (lane == 0) {
            int pidx = colt*64 + b;
            cst(&p.pm[pidx], m); cst(&p.pd[pidx], ls);
            cst(&p.pv[pidx], av); csti(&p.pi[pidx], ai);
          }
        }
      }
    }
    gbar(flags, ++ep);

    // ---- G: per-b merge; outputs + next embed ----
    if (wgid < BATCH) {
      int b = wgid;
      float* Lm = sm; float* Ld = sm + 128; float* Lv = sm + 256;
      int* Li = (int*)(sm + 384); int* Lei = Li + 128;
      if (tid < NCOLT) {
        Lm[tid] = cld(&p.pm[tid*64 + b]);
        Ld[tid] = cld(&p.pd[tid*64 + b]);
        Lv[tid] = cld(&p.pv[tid*64 + b]);
        Li[tid] = cldi(&p.pi[tid*64 + b]);
      }
      __syncthreads();
      if (tid == 0) {
        float gmax = -1e30f;
        for (int t2 = 0; t2 < NCOLT; ++t2) gmax = fmaxf(gmax, Lm[t2]);
        float Ssum = 0.f;
        for (int t2 = 0; t2 < NCOLT; ++t2) Ssum += Ld[t2] * expf(Lm[t2] - gmax);
        float bvv = -1e30f; int bi = VOC;
        for (int t2 = 0; t2 < NCOLT; ++t2)
          if (Lv[t2] > bvv || (Lv[t2] == bvv && Li[t2] < bi)) { bvv = Lv[t2]; bi = Li[t2]; }
        int run = 1;
        for (int j = 1; j <= i; ++j) if (p.target[b*BPTT + j] == 2) run = 0;
        float p2 = expf(cld(&p.logits[(long)b*VOC + 2]) - gmax) / Ssum;
        p.out_eos[b*BPTT + i] = p2;
        p.out_words[b*BPTT + i] = run ? (float)bi : 0.f;
        cst(&p.gS[b*2], gmax);
        cst(&p.gS[b*2+1], Ssum);
        csti(&p.maskS[b], run);
        Lei[0] = bi;
      }
      __syncthreads();
      if (i + 1 < BPTT && tid < D) {
        int ei = Lei[0];
        cst(&p.embeds[((long)(i+1)*BATCH + b)*D + tid], p.emb_table[(long)ei*D + tid]);
      }
    }
    gbar(flags, ++ep);
  } // steps

  // ---- final H: out_probs update for step 19 ----
  if (wgid < NCOLT) {
    float* gm = sm; float* ss = sm + 64; int* mk = (int*)(sm + 128);
    if (tid < 64) {
      gm[tid] = cld(&p.gS[tid*2]); ss[tid] = cld(&p.gS[tid*2+1]);
      mk[tid] = cldi(&p.maskS[tid]);
    }
    __syncthreads();
    int cbase = wgid*256;
    for (int idx = tid; idx < BATCH*256; idx += NTHR) {
      int b = idx >> 8, c = cbase + (idx & 255);
      if (c < VOC && mk[b]) {
        float l = cld(&p.logits[(long)b*VOC + c]);
        float pr = expf(l - gm[b]) / ss[b];
        float* op = &p.out_probs[(long)b*VOC + c];
        *op = fmaxf(*op, pr);
      }
    }
  }
}

// ---------------- host ----------------
extern "C" void kernel_launch(void* const* d_in, const int* in_sizes, int n_in,
                              void* d_out, int out_size, void* d_ws, size_t ws_size,
                              hipStream_t stream) {
  Params P;
  P.image_feats = (const float*)d_in[0];
  P.target      = (const int*)  d_in[1];
  P.emb_table   = (const float*)d_in[2];
  P.W_g2e       = (const float*)d_in[3];
  P.b_g2e       = (const float*)d_in[4];
  P.W_out       = (const float*)d_in[5];
  P.b_out       = (const float*)d_in[6];
  P.Wqkv        = (const float*)d_in[7];
  P.bqkv        = (const float*)d_in[8];
  P.Wo          = (const float*)d_in[9];
  P.bo          = (const float*)d_in[10];
  P.W1          = (const float*)d_in[11];
  P.b1          = (const float*)d_in[12];
  P.W2          = (const float*)d_in[13];
  P.b2          = (const float*)d_in[14];
  P.g1          = (const float*)d_in[15];
  P.be1         = (const float*)d_in[16];
  P.g2          = (const float*)d_in[17];
  P.be2         = (const float*)d_in[18];

  float* out_probs = (float*)d_out;
  P.out_probs = out_probs;
  P.out_words = out_probs + (long)BATCH*VOC;
  P.out_eos   = P.out_words + BATCH*BPTT;

  char* ws = (char*)d_ws;
  P.embeds = (float*)ws;  ws += sizeof(float)*(long)NMAX*D;
  P.xcur   = (float*)ws;  ws += sizeof(float)*(long)NMAX*D;
  P.xln1   = (float*)ws;  ws += sizeof(float)*(long)NMAX*D;
  P.qkvb0  = (float*)ws;  ws += sizeof(float)*(long)NMAX*3*D;
  P.qkvb   = (float*)ws;  ws += sizeof(float)*(long)NMAX*3*D;
  P.pp     = (float*)ws;  ws += sizeof(float)*(long)4*NMAX*D;
  P.fp     = (float*)ws;  ws += sizeof(float)*(long)8*NMAX*D;
  P.logits = (float*)ws;  ws += sizeof(float)*(long)BATCH*VOC;
  P.pm     = (float*)ws;  ws += sizeof(float)*NCOLT*64;
  P.pd     = (float*)ws;  ws += sizeof(float)*NCOLT*64;
  P.pv     = (float*)ws;  ws += sizeof(float)*NCOLT*64;
  P.gS     = (float*)ws;  ws += sizeof(float)*128;
  P.pi     = (int*)ws;    ws += sizeof(int)*NCOLT*64;
  P.maskS  = (int*)ws;    ws += sizeof(int)*64;
  P.flags  = (unsigned*)ws; ws += sizeof(unsigned)*NWG*32;

  static bool inited = false;
  if (!inited) {
    hipFuncSetAttribute((const void*)mega,
                        hipFuncAttributeMaxDynamicSharedMemorySize, 65536);
    inited = true;
  }

  hipMemsetAsync(P.flags, 0, sizeof(unsigned)*NWG*32, stream);
  void* args[] = { &P };
  hipError_t err = hipLaunchCooperativeKernel((void*)mega, dim3(NWG), dim3(NTHR),
                                              args, 65536, stream);
  if (err != hipSuccess) {
    // 256 blocks x 64KB LDS = 1 block/CU on 256 CUs: co-resident by capacity.
    hipLaunchKernelGGL(mega, dim3(NWG), dim3(NTHR), 65536, stream, P);
  }
}

// Round 6
// 9580.329 us; speedup vs baseline: 2.3670x; 1.0991x over previous
//
#include <hip/hip_runtime.h>
#include <math.h>

#define D 256
#define NH 4
#define HDIM 64
#define FFD 2048
#define NL 3
#define VOC 30000
#define BPTT 20
#define BATCH 64
#define NMAX (BPTT*BATCH)   /* 1280 */
#define NCOLT 118           /* ceil(VOC/256) */
#define TROWS 32
#define NWG 256
#define NTHR 512

struct Params {
  const float* image_feats; const int* target; const float* emb_table;
  const float* W_g2e; const float* b_g2e;
  const float* W_out; const float* b_out;
  const float* Wqkv; const float* bqkv;
  const float* Wo;   const float* bo;
  const float* W1;   const float* b1;
  const float* W2;   const float* b2;
  const float* g1;   const float* be1;
  const float* g2;   const float* be2;
  float* out_probs; float* out_words; float* out_eos;
  float* embeds; float* xcur; float* xln1; float* qkvb0; float* qkvb;
  float* pp; float* fp; float* logits;
  float* pm; float* pd; float* pv; float* gS;
  int* pi; int* maskS;
  unsigned* flags;
};

// ---- device-coherent (cross-XCD) access via LLC ----
__device__ __forceinline__ float cld(const float* p) {
  return __hip_atomic_load(p, __ATOMIC_RELAXED, __HIP_MEMORY_SCOPE_AGENT);
}
__device__ __forceinline__ void cst(float* p, float v) {
  __hip_atomic_store(p, v, __ATOMIC_RELAXED, __HIP_MEMORY_SCOPE_AGENT);
}
__device__ __forceinline__ int cldi(const int* p) {
  return __hip_atomic_load(p, __ATOMIC_RELAXED, __HIP_MEMORY_SCOPE_AGENT);
}
__device__ __forceinline__ void csti(int* p, int v) {
  __hip_atomic_store(p, v, __ATOMIC_RELAXED, __HIP_MEMORY_SCOPE_AGENT);
}
// 8-byte coherent pair accesses (8B-aligned addresses only)
__device__ __forceinline__ float2 cld2(const float* p) {
  unsigned long long u = __hip_atomic_load((const unsigned long long*)p,
                                           __ATOMIC_RELAXED, __HIP_MEMORY_SCOPE_AGENT);
  union { unsigned long long u; float2 f; } x; x.u = u; return x.f;
}
__device__ __forceinline__ void cst2(float* p, float a, float b) {
  union { unsigned long long u; float f[2]; } x; x.f[0] = a; x.f[1] = b;
  __hip_atomic_store((unsigned long long*)p, x.u,
                     __ATOMIC_RELAXED, __HIP_MEMORY_SCOPE_AGENT);
}

__device__ __forceinline__ float wredsum(float s) {
  for (int off = 32; off; off >>= 1) s += __shfl_down(s, off);
  return __shfl(s, 0);
}
__device__ __forceinline__ float wredmax(float m) {
  for (int off = 32; off; off >>= 1) m = fmaxf(m, __shfl_down(m, off));
  return __shfl(m, 0);
}

// ---- broadcast grid barrier: arrive = 1 flag store/block; block 0 aggregates
// all flags and stores a single release word; other blocks poll ONLY that word
// with one scalar load (kills the 256-line x 256-block poll storm of r4/r5).
// Data correctness: producers' cst stores drain (vmcnt 0) before the flag
// store; consumers load after the dependent poll-exit + __syncthreads.
__device__ __forceinline__ void gbar(unsigned* flags, unsigned epoch) {
  unsigned* rel = flags + NWG*32;
  asm volatile("s_waitcnt vmcnt(0) lgkmcnt(0)" ::: "memory");
  __syncthreads();
  if (blockIdx.x == 0) {
    int ok;
    do {
      int mine = 1;
      if (threadIdx.x > 0 && threadIdx.x < NWG)
        mine = ((int)(__hip_atomic_load(&flags[(unsigned)threadIdx.x * 32u],
                      __ATOMIC_RELAXED, __HIP_MEMORY_SCOPE_AGENT) - epoch) >= 0);
      ok = __syncthreads_and(mine);
      if (!ok) __builtin_amdgcn_s_sleep(1);
    } while (!ok);
    if (threadIdx.x == 0)
      __hip_atomic_store(rel, epoch, __ATOMIC_RELAXED, __HIP_MEMORY_SCOPE_AGENT);
  } else {
    if (threadIdx.x == 0) {
      __hip_atomic_store(&flags[(unsigned)blockIdx.x * 32u], epoch,
                         __ATOMIC_RELAXED, __HIP_MEMORY_SCOPE_AGENT);
      while ((int)(__hip_atomic_load(rel, __ATOMIC_RELAXED,
                   __HIP_MEMORY_SCOPE_AGENT) - epoch) < 0)
        __builtin_amdgcn_s_sleep(2);
    }
    __syncthreads();
  }
  asm volatile("" ::: "memory");
}

// ---- stage 32x256 rows (coherent src, 8B loads) ----
__device__ __forceinline__ void stage32(float (*As)[D], const float* src, long row0) {
  for (int idx = threadIdx.x; idx < TROWS*D/2; idx += NTHR) {
    int r = idx >> 7, c2 = (idx & 127)*2;
    float2 v = cld2(src + (row0 + r)*(long)D + c2);
    As[r][c2] = v.x; As[r][c2+1] = v.y;
  }
}

// ---- stage 32 rows with fused residual+partials sum and LayerNorm (8B) ----
__device__ __forceinline__ void stageLN(float (*As)[D], const float* resid, long row0,
    const float* parts, int nparts, long pstride,
    const float* bias, const float* g, const float* be, float* wr) {
  const int tid = threadIdx.x;
  for (int idx = tid; idx < TROWS*D/2; idx += NTHR) {
    int r = idx >> 7, c2 = (idx & 127)*2;
    long row = row0 + r;
    float2 v = cld2(resid + row*D + c2);
    float vx = v.x + bias[c2], vy = v.y + bias[c2+1];
    for (int q = 0; q < nparts; ++q) {
      float2 pv = cld2(parts + (long)q*pstride + row*D + c2);
      vx += pv.x; vy += pv.y;
    }
    As[r][c2] = vx; As[r][c2+1] = vy;
  }
  __syncthreads();
  const int lane = tid & 63, w = tid >> 6;
#pragma unroll
  for (int j = 0; j < 4; ++j) {
    int r = w*4 + j;
    float4 x = *(float4*)&As[r][lane*4];
    float mu = wredsum(x.x+x.y+x.z+x.w) * (1.f/D);
    float dx = x.x-mu, dy = x.y-mu, dz = x.z-mu, dw = x.w-mu;
    float var = wredsum(dx*dx+dy*dy+dz*dz+dw*dw) * (1.f/D);
    float inv = 1.f/sqrtf(var + 1e-5f);
    float4 gg = *(const float4*)&g[lane*4];
    float4 bb = *(const float4*)&be[lane*4];
    float4 o;
    o.x = dx*inv*gg.x + bb.x; o.y = dy*inv*gg.y + bb.y;
    o.z = dz*inv*gg.z + bb.z; o.w = dw*inv*gg.w + bb.w;
    *(float4*)&As[r][lane*4] = o;
    if (wr) {
      long row = row0 + r;
      cst2(&wr[row*D + lane*4],     o.x, o.y);
      cst2(&wr[row*D + lane*4 + 2], o.z, o.w);
    }
  }
  __syncthreads();
}

// ---- 32x256 @ 256xM tile with 512 threads: wave w rows w*4+j, lane cols lane*4..+3
__device__ __forceinline__ void mm32w(const float (*As)[D], const float* __restrict__ Wp,
                                      long M, float acc[4][4]) {
  const int r0 = (threadIdx.x >> 6) * 4;
  for (int kk = 0; kk < D; kk += 4) {
    float w[4][4];
#pragma unroll
    for (int q = 0; q < 4; ++q)
      *(float4*)w[q] = *(const float4*)(Wp + (long)(kk+q)*M);
#pragma unroll
    for (int j = 0; j < 4; ++j) {
      float a[4];
      *(float4*)a = *(const float4*)&As[r0+j][kk];
#pragma unroll
      for (int c = 0; c < 4; ++c)
#pragma unroll
        for (int q = 0; q < 4; ++q)
          acc[j][c] += a[q]*w[q][c];
    }
  }
}

__global__ __launch_bounds__(NTHR, 2) void mega(Params p) {
  extern __shared__ char smraw[];
  float (*As)[D] = (float(*)[D])smraw;                 // 32KB
  float (*Bs)[D] = (float(*)[D])(smraw + TROWS*D*4);   // 32KB
  float* sm = (float*)smraw;
  const int tid = threadIdx.x, wgid = blockIdx.x;
  const int lane = tid & 63, wave = tid >> 6;
  unsigned ep = 0;
  unsigned* flags = p.flags;

  // ================= init: img embed (blocks 0..63) =================
  if (wgid < BATCH) {
    int b = wgid;
    for (int idx = tid; idx < 2048; idx += NTHR) sm[idx] = p.image_feats[b*2048 + idx];
    __syncthreads();
    if (tid < D) {
      float acc = 0.f;
      for (int k = 0; k < 2048; k += 4) {
        float4 xv = *(const float4*)&sm[k];
        acc += xv.x * p.W_g2e[(k+0)*D + tid];
        acc += xv.y * p.W_g2e[(k+1)*D + tid];
        acc += xv.z * p.W_g2e[(k+2)*D + tid];
        acc += xv.w * p.W_g2e[(k+3)*D + tid];
      }
      cst(&p.embeds[(long)b*D + tid], acc + p.b_g2e[tid]);
    }
  }
  gbar(flags, ++ep);

  // ================= decode loop =================
  for (int i = 0; i < BPTT; ++i) {
    const int S = i + 1;

    // ---- PH1: A0 new-row qkv (blocks 118..123) || H(i-1) probs (0..117) ----
    if (wgid >= NCOLT && wgid < NCOLT + 6) {
      int idx = wgid - NCOLT;
      int tt = idx & 1, cp = idx >> 1;
      long row0 = (long)i*BATCH + tt*TROWS;
      stage32(As, p.embeds, row0);
      __syncthreads();
      float acc[4][4] = {};
      int col = cp*256 + lane*4;
      mm32w(As, p.Wqkv + col, 3*D, acc);
      float bv[4]; *(float4*)bv = *(const float4*)(p.bqkv + col);
      const int r0 = wave*4;
      for (int j = 0; j < 4; ++j) {
        long row = row0 + r0 + j;
        cst2(&p.qkvb0[row*768 + col],     acc[j][0] + bv[0], acc[j][1] + bv[1]);
        cst2(&p.qkvb0[row*768 + col + 2], acc[j][2] + bv[2], acc[j][3] + bv[3]);
      }
    } else if (wgid < NCOLT && i > 0) {
      float* gm = sm; float* ss = sm + 64; int* mk = (int*)(sm + 128);
      if (tid < 64) {
        gm[tid] = cld(&p.gS[tid*2]); ss[tid] = cld(&p.gS[tid*2+1]);
        mk[tid] = cldi(&p.maskS[tid]);
      }
      __syncthreads();
      int cbase = wgid*256;
      for (int idx = tid; idx < BATCH*128; idx += NTHR) {
        int b = idx >> 7, c = cbase + (idx & 127)*2;
        if (c < VOC && (i-1 == 0 || mk[b])) {
          float2 l = cld2(&p.logits[(long)b*VOC + c]);
          float pr0 = expf(l.x - gm[b]) / ss[b];
          float pr1 = expf(l.y - gm[b]) / ss[b];
          float* op = &p.out_probs[(long)b*VOC + c];
          if (i-1 == 0) { op[0] = pr0; op[1] = pr1; }
          else { op[0] = fmaxf(op[0], pr0); op[1] = fmaxf(op[1], pr1); }
        }
      }
    }
    gbar(flags, ++ep);

    for (int l = 0; l < NL; ++l) {
      // ---- B: attention + per-head proj partial (block = (b,h)) ----
      {
        const float* src = (l == 0) ? p.qkvb0 : p.qkvb;
        float* qs = sm; float* ks = sm + 1280; float* vs = sm + 2560;
        float* ps = sm + 3840;
        int b = wgid & 63, h = wgid >> 6;
        for (int idx = tid; idx < S*32; idx += NTHR) {
          int s = idx >> 5, d2 = (idx & 31)*2;
          long base = (long)(s*BATCH + b)*768 + h*HDIM + d2;
          float2 qv = cld2(&src[base]);
          float2 kv = cld2(&src[base + D]);
          float2 vv = cld2(&src[base + 2*D]);
          qs[s*HDIM+d2] = qv.x; qs[s*HDIM+d2+1] = qv.y;
          ks[s*HDIM+d2] = kv.x; ks[s*HDIM+d2+1] = kv.y;
          vs[s*HDIM+d2] = vv.x; vs[s*HDIM+d2+1] = vv.y;
        }
        __syncthreads();
        const float* Wo2 = p.Wo + (long)l*D*D + (long)h*HDIM*D;
        if (l < NL-1) {
          for (int idx = tid; idx < S*S; idx += NTHR) {
            int si = idx / S, ti = idx - si*S;
            float a = 0.f;
#pragma unroll 8
            for (int k = 0; k < HDIM; ++k) a += qs[si*HDIM+k]*ks[ti*HDIM+k];
            ps[si*(BPTT+1)+ti] = a * 0.125f;
          }
          __syncthreads();
          for (int r = wave; r < S; r += 8) {
            float v = (lane < S) ? ps[r*(BPTT+1)+lane] : -1e30f;
            float m = wredmax(v);
            float e = (lane < S) ? expf(v - m) : 0.f;
            float ssum = wredsum(e);
            if (lane < S) ps[r*(BPTT+1)+lane] = e / ssum;
          }
          __syncthreads();
          for (int idx = tid; idx < S*HDIM; idx += NTHR) {
            int s = idx >> 6, d = idx & 63;
            float a = 0.f;
            for (int t2 = 0; t2 < S; ++t2) a += ps[s*(BPTT+1)+t2]*vs[t2*HDIM+d];
            qs[idx] = a;   // o overwrites q (q dead after scores)
          }
          __syncthreads();
          int c0 = lane*4;
          float acc[3][4] = {};
          for (int k = 0; k < HDIM; ++k) {
            float4 w = *(const float4*)&Wo2[(long)k*D + c0];
#pragma unroll
            for (int jj = 0; jj < 3; ++jj) {
              int r = wave + 8*jj;
              float a = (r < S) ? qs[r*HDIM + k] : 0.f;
              acc[jj][0]+=a*w.x; acc[jj][1]+=a*w.y; acc[jj][2]+=a*w.z; acc[jj][3]+=a*w.w;
            }
          }
          for (int jj = 0; jj < 3; ++jj) {
            int r = wave + 8*jj;
            if (r < S) {
              long row = (long)r*BATCH + b;
              cst2(&p.pp[((long)h*NMAX + row)*D + c0],     acc[jj][0], acc[jj][1]);
              cst2(&p.pp[((long)h*NMAX + row)*D + c0 + 2], acc[jj][2], acc[jj][3]);
            }
          }
        } else {
          // l==2: only the last q-row (s=i) is ever consumed
          if (tid < S) {
            float a = 0.f;
            for (int k = 0; k < HDIM; ++k) a += qs[i*HDIM+k]*ks[tid*HDIM+k];
            ps[tid] = a * 0.125f;
          }
          __syncthreads();
          if (wave == 0) {
            float v = (lane < S) ? ps[lane] : -1e30f;
            float m = wredmax(v);
            float e = (lane < S) ? expf(v - m) : 0.f;
            float ssum = wredsum(e);
            if (lane < S) ps[lane] = e / ssum;
          }
          __syncthreads();
          if (tid < HDIM) {
            float a = 0.f;
            for (int t2 = 0; t2 < S; ++t2) a += ps[t2]*vs[t2*HDIM+tid];
            qs[tid] = a;
          }
          __syncthreads();
          if (tid < 128) {
            int c2 = tid*2;
            float a0 = 0.f, a1 = 0.f;
            for (int k = 0; k < HDIM; ++k) {
              a0 += qs[k]*Wo2[(long)k*D + c2];
              a1 += qs[k]*Wo2[(long)k*D + c2 + 1];
            }
            cst2(&p.pp[((long)h*NMAX + (long)i*BATCH + b)*D + c2], a0, a1);
          }
        }
      }
      gbar(flags, ++ep);

      // ---- D: LN1-fused stage + ff1(relu) + ff2 partial ----
      {
        const float* resid = (l == 0) ? p.embeds : p.xcur;
        const float* bol = p.bo + l*D;
        const float* g1l = p.g1 + l*D; const float* be1l = p.be1 + l*D;
        const float* W1l = p.W1 + (long)l*D*FFD;
        const float* b1l = p.b1 + (long)l*FFD;
        const float* W2l = p.W2 + (long)l*FFD*D;
        const int y = wgid & 7, slot = wgid >> 3;
        const int nrt = (l == NL-1) ? 2 : 2*S;
        const long rbase = (l == NL-1) ? (long)i*BATCH : 0;
        for (int tt = slot; tt < nrt; tt += 32) {
          long row0 = rbase + (long)tt*TROWS;
          stageLN(As, resid, row0, p.pp, 4, (long)NMAX*D, bol, g1l, be1l,
                  (y == 0) ? p.xln1 : nullptr);
          float acc1[4][4] = {};
          int fcol = y*256 + lane*4;
          mm32w(As, W1l + fcol, FFD, acc1);
          float bv[4]; *(float4*)bv = *(const float4*)(b1l + fcol);
          const int r0 = wave*4;
          for (int j = 0; j < 4; ++j)
            for (int c = 0; c < 4; ++c)
              Bs[r0+j][lane*4+c] = fmaxf(acc1[j][c] + bv[c], 0.f);
          __syncthreads();
          float acc2[4][4] = {};
          mm32w(Bs, W2l + (long)(y*256)*D + lane*4, D, acc2);
          for (int j = 0; j < 4; ++j) {
            long row = row0 + r0 + j;
            cst2(&p.fp[((long)y*NMAX + row)*D + lane*4],     acc2[j][0], acc2[j][1]);
            cst2(&p.fp[((long)y*NMAX + row)*D + lane*4 + 2], acc2[j][2], acc2[j][3]);
          }
          __syncthreads();
        }
      }
      gbar(flags, ++ep);

      // ---- AE (l<2): LN2-fused stage + qkv for layer l+1 ----
      if (l + 1 < NL) {
        const float* b2l = p.b2 + l*D;
        const float* g2l = p.g2 + l*D; const float* be2l = p.be2 + l*D;
        const float* Wl = p.Wqkv + (long)(l+1)*D*768;
        const float* bl = p.bqkv + (long)(l+1)*768;
        for (int t = wgid; t < 6*S; t += NWG) {
          int tt = t % (2*S), cp = t / (2*S);
          long row0 = (long)tt*TROWS;
          stageLN(As, p.xln1, row0, p.fp, 8, (long)NMAX*D, b2l, g2l, be2l,
                  (cp == 0) ? p.xcur : nullptr);
          float acc[4][4] = {};
          int col = cp*256 + lane*4;
          mm32w(As, Wl + col, 768, acc);
          float bv[4]; *(float4*)bv = *(const float4*)(bl + col);
          const int r0 = wave*4;
          for (int j = 0; j < 4; ++j) {
            long row = row0 + r0 + j;
            cst2(&p.qkvb[row*768 + col],     acc[j][0] + bv[0], acc[j][1] + bv[1]);
            cst2(&p.qkvb[row*768 + col + 2], acc[j][2] + bv[2], acc[j][3] + bv[3]);
          }
          __syncthreads();
        }
        gbar(flags, ++ep);
      }
    } // layers

    // ---- F: LN2-fused stage + logits tiles (XCD-stable colt swizzle) ----
    {
      const float* b2l = p.b2 + (NL-1)*D;
      const float* g2l = p.g2 + (NL-1)*D; const float* be2l = p.be2 + (NL-1)*D;
      const int x = wgid & 7, slot = wgid >> 3;
      const int rowt = slot & 1, cq = slot >> 1;
      const int colt = cq*8 + x;
      if (cq < 15 && colt < NCOLT) {
        long row0 = (long)i*BATCH + rowt*TROWS;
        stageLN(As, p.xln1, row0, p.fp, 8, (long)NMAX*D, b2l, g2l, be2l, nullptr);
        int col = colt*256 + lane*4;
        int colL = col > VOC-4 ? VOC-4 : col;
        float acc[4][4] = {};
        mm32w(As, p.W_out + colL, VOC, acc);
        float bv[4]; *(float4*)bv = *(const float4*)(p.b_out + colL);
        bool valid = (col < VOC);
        const int r0 = wave*4;
        for (int j = 0; j < 4; ++j) {
          int b = rowt*TROWS + r0 + j;
          float v4[4]; float lm = -1e30f;
          for (int c = 0; c < 4; ++c) v4[c] = acc[j][c] + bv[c];
          if (valid) {
            cst2(&p.logits[(long)b*VOC + col],     v4[0], v4[1]);
            cst2(&p.logits[(long)b*VOC + col + 2], v4[2], v4[3]);
            for (int c = 0; c < 4; ++c) lm = fmaxf(lm, v4[c]);
          }
          float m = wredmax(lm);
          float ls = 0.f;
          if (valid) for (int c = 0; c < 4; ++c) ls += expf(v4[c] - m);
          for (int off = 32; off; off >>= 1) ls += __shfl_down(ls, off);
          float av = -1e30f; int ai = VOC;
          if (valid) for (int c = 0; c < 4; ++c) if (v4[c] > av) { av = v4[c]; ai = col + c; }
          for (int off = 32; off; off >>= 1) {
            float av2 = __shfl_down(av, off); int ai2 = __shfl_down(ai, off);
            if (av2 > av || (av2 == av && ai2 < ai)) { av = av2; ai = ai2; }
          }
          if (lane == 0) {
            int pidx = colt*64 + b;
            cst(&p.pm[pidx], m); cst(&p.pd[pidx], ls);
            cst(&p.pv[pidx], av); csti(&p.pi[pidx], ai);
          }
        }
      }
    }
    gbar(flags, ++ep);

    // ---- G: per-b merge; outputs + next embed ----
    if (wgid < BATCH) {
      int b = wgid;
      float* Lm = sm; float* Ld = sm + 128; float* Lv = sm + 256;
      int* Li = (int*)(sm + 384); int* Lei = Li + 128;
      if (tid < NCOLT) {
        Lm[tid] = cld(&p.pm[tid*64 + b]);
        Ld[tid] = cld(&p.pd[tid*64 + b]);
        Lv[tid] = cld(&p.pv[tid*64 + b]);
        Li[tid] = cldi(&p.pi[tid*64 + b]);
      }
      __syncthreads();
      if (tid == 0) {
        float gmax = -1e30f;
        for (int t2 = 0; t2 < NCOLT; ++t2) gmax = fmaxf(gmax, Lm[t2]);
        float Ssum = 0.f;
        for (int t2 = 0; t2 < NCOLT; ++t2) Ssum += Ld[t2] * expf(Lm[t2] - gmax);
        float bvv = -1e30f; int bi = VOC;
        for (int t2 = 0; t2 < NCOLT; ++t2)
          if (Lv[t2] > bvv || (Lv[t2] == bvv && Li[t2] < bi)) { bvv = Lv[t2]; bi = Li[t2]; }
        int run = 1;
        for (int j = 1; j <= i; ++j) if (p.target[b*BPTT + j] == 2) run = 0;
        float p2 = expf(cld(&p.logits[(long)b*VOC + 2]) - gmax) / Ssum;
        p.out_eos[b*BPTT + i] = p2;
        p.out_words[b*BPTT + i] = run ? (float)bi : 0.f;
        cst(&p.gS[b*2], gmax);
        cst(&p.gS[b*2+1], Ssum);
        csti(&p.maskS[b], run);
        Lei[0] = bi;
      }
      __syncthreads();
      if (i + 1 < BPTT && tid < 128) {
        int ei = Lei[0];
        int c2 = tid*2;
        cst2(&p.embeds[((long)(i+1)*BATCH + b)*D + c2],
             p.emb_table[(long)ei*D + c2], p.emb_table[(long)ei*D + c2 + 1]);
      }
    }
    gbar(flags, ++ep);
  } // steps

  // ---- final H: out_probs update for step 19 ----
  if (wgid < NCOLT) {
    float* gm = sm; float* ss = sm + 64; int* mk = (int*)(sm + 128);
    if (tid < 64) {
      gm[tid] = cld(&p.gS[tid*2]); ss[tid] = cld(&p.gS[tid*2+1]);
      mk[tid] = cldi(&p.maskS[tid]);
    }
    __syncthreads();
    int cbase = wgid*256;
    for (int idx = tid; idx < BATCH*128; idx += NTHR) {
      int b = idx >> 7, c = cbase + (idx & 127)*2;
      if (c < VOC && mk[b]) {
        float2 l = cld2(&p.logits[(long)b*VOC + c]);
        float pr0 = expf(l.x - gm[b]) / ss[b];
        float pr1 = expf(l.y - gm[b]) / ss[b];
        float* op = &p.out_probs[(long)b*VOC + c];
        op[0] = fmaxf(op[0], pr0);
        op[1] = fmaxf(op[1], pr1);
      }
    }
  }
}

// ---------------- host ----------------
extern "C" void kernel_launch(void* const* d_in, const int* in_sizes, int n_in,
                              void* d_out, int out_size, void* d_ws, size_t ws_size,
                              hipStream_t stream) {
  Params P;
  P.image_feats = (const float*)d_in[0];
  P.target      = (const int*)  d_in[1];
  P.emb_table   = (const float*)d_in[2];
  P.W_g2e       = (const float*)d_in[3];
  P.b_g2e       = (const float*)d_in[4];
  P.W_out       = (const float*)d_in[5];
  P.b_out       = (const float*)d_in[6];
  P.Wqkv        = (const float*)d_in[7];
  P.bqkv        = (const float*)d_in[8];
  P.Wo          = (const float*)d_in[9];
  P.bo          = (const float*)d_in[10];
  P.W1          = (const float*)d_in[11];
  P.b1          = (const float*)d_in[12];
  P.W2          = (const float*)d_in[13];
  P.b2          = (const float*)d_in[14];
  P.g1          = (const float*)d_in[15];
  P.be1         = (const float*)d_in[16];
  P.g2          = (const float*)d_in[17];
  P.be2         = (const float*)d_in[18];

  float* out_probs = (float*)d_out;
  P.out_probs = out_probs;
  P.out_words = out_probs + (long)BATCH*VOC;
  P.out_eos   = P.out_words + BATCH*BPTT;

  char* ws = (char*)d_ws;
  P.embeds = (float*)ws;  ws += sizeof(float)*(long)NMAX*D;
  P.xcur   = (float*)ws;  ws += sizeof(float)*(long)NMAX*D;
  P.xln1   = (float*)ws;  ws += sizeof(float)*(long)NMAX*D;
  P.qkvb0  = (float*)ws;  ws += sizeof(float)*(long)NMAX*3*D;
  P.qkvb   = (float*)ws;  ws += sizeof(float)*(long)NMAX*3*D;
  P.pp     = (float*)ws;  ws += sizeof(float)*(long)4*NMAX*D;
  P.fp     = (float*)ws;  ws += sizeof(float)*(long)8*NMAX*D;
  P.logits = (float*)ws;  ws += sizeof(float)*(long)BATCH*VOC;
  P.pm     = (float*)ws;  ws += sizeof(float)*NCOLT*64;
  P.pd     = (float*)ws;  ws += sizeof(float)*NCOLT*64;
  P.pv     = (float*)ws;  ws += sizeof(float)*NCOLT*64;
  P.gS     = (float*)ws;  ws += sizeof(float)*128;
  P.pi     = (int*)ws;    ws += sizeof(int)*NCOLT*64;
  P.maskS  = (int*)ws;    ws += sizeof(int)*64;
  P.flags  = (unsigned*)ws; ws += sizeof(unsigned)*(NWG*32 + 32); // +release word line

  static bool inited = false;
  if (!inited) {
    hipFuncSetAttribute((const void*)mega,
                        hipFuncAttributeMaxDynamicSharedMemorySize, 65536);
    inited = true;
  }

  hipMemsetAsync(P.flags, 0, sizeof(unsigned)*(NWG*32 + 32), stream);
  void* args[] = { &P };
  hipError_t err = hipLaunchCooperativeKernel((void*)mega, dim3(NWG), dim3(NTHR),
                                              args, 65536, stream);
  if (err != hipSuccess) {
    // 256 blocks x 64KB LDS = 1 block/CU on 256 CUs: co-resident by capacity.
    hipLaunchKernelGGL(mega, dim3(NWG), dim3(NTHR), 65536, stream, P);
  }
}